// Round 5
// baseline (853.656 us; speedup 1.0000x reference)
//
#include <hip/hip_runtime.h>
#include <hip/hip_bf16.h>
#include <cstdint>

#define HIDDEN 4096
#define NH 32
#define NKV 8
#define HD 128
#define SEQ 2048
#define BSZ 2
#define QKVN 6144          // fused QKV projection width
#define QKVLD 6144         // row stride of fused QKV buffer

using bf16x8 = __attribute__((ext_vector_type(8))) short;
using f32x4  = __attribute__((ext_vector_type(4))) float;

__device__ __forceinline__ ushort f2bf(float f) {
  union { float f; uint32_t u; } v; v.f = f;
  uint32_t r = (v.u + 0x7FFFu + ((v.u >> 16) & 1u)) >> 16;  // RNE
  return (ushort)r;
}
__device__ __forceinline__ float bf2f(ushort s) {
  union { uint32_t u; float f; } v; v.u = ((uint32_t)s) << 16;
  return v.f;
}

__device__ __forceinline__ void gload_lds16(const void* g, void* l) {
  __builtin_amdgcn_global_load_lds(
      (const __attribute__((address_space(1))) void*)g,
      (__attribute__((address_space(3))) void*)l, 16, 0, 0);
}

// ---------------------------------------------------------------------------
// fp32 -> bf16 elementwise convert (vectorized, 8 elems/thread)
// ---------------------------------------------------------------------------
__global__ __launch_bounds__(256)
void cvt_bf16_kernel(const float* __restrict__ X, ushort* __restrict__ Xb, int n8) {
  int t = blockIdx.x * 256 + threadIdx.x;
  if (t >= n8) return;
  size_t i = (size_t)t * 8;
  float4 a = *(const float4*)(X + i);
  float4 b = *(const float4*)(X + i + 4);
  uint4 p;
  p.x = (uint)f2bf(a.x) | ((uint)f2bf(a.y) << 16);
  p.y = (uint)f2bf(a.z) | ((uint)f2bf(a.w) << 16);
  p.z = (uint)f2bf(b.x) | ((uint)f2bf(b.y) << 16);
  p.w = (uint)f2bf(b.z) | ((uint)f2bf(b.w) << 16);
  *(uint4*)(Xb + i) = p;
}

// ---------------------------------------------------------------------------
// W[K][N] fp32 -> WT[N][K] bf16 (32x32 LDS tile transpose)
// ---------------------------------------------------------------------------
__global__ __launch_bounds__(256)
void transpose_bf16_kernel(const float* __restrict__ W, ushort* __restrict__ WT,
                           int K, int N) {
  __shared__ ushort tile[32][33];
  const int k0 = blockIdx.y * 32, n0 = blockIdx.x * 32;
  const int tx = threadIdx.x & 31, ty = threadIdx.x >> 5;  // ty 0..7
  for (int i = 0; i < 4; ++i) {
    int k = ty + i * 8;
    tile[k][tx] = f2bf(W[(size_t)(k0 + k) * N + n0 + tx]);
  }
  __syncthreads();
  for (int i = 0; i < 4; ++i) {
    int n = ty + i * 8;
    WT[(size_t)(n0 + n) * K + k0 + tx] = tile[tx][n];
  }
}

// ---------------------------------------------------------------------------
// GEMM: C[MxN] = A[MxK] * BT[NxK]^T, bf16 inputs.
// 128x128 tile, BK=64, 4 waves, ping-pong double-buffered LDS (1 barrier/step),
// global_load_lds width-16, XCD-chunked swizzle (M-fastest within N-band).
// ---------------------------------------------------------------------------
template<int OUT_BF16>
__global__ __launch_bounds__(256)
void gemm_bf16_kernel(const ushort* __restrict__ A, const ushort* __restrict__ BT,
                      void* __restrict__ Cp, int M, int N, int K) {
  __shared__ ushort As[2][128 * 64];   // 32 KB
  __shared__ ushort Bs[2][128 * 64];   // 32 KB
  const int tid = threadIdx.x;
  const int lane = tid & 63, wave = tid >> 6;
  const int l15 = lane & 15, l4 = lane >> 4;
  const int wr = (wave >> 1) * 64, wc = (wave & 1) * 64;

  // ---- XCD-chunked swizzle: XCD x owns N-band [x*NT_N/8, (x+1)*NT_N/8) ----
  const int mtile = M >> 7, ntile = N >> 7;    // grid = mtile*ntile, ntile%8==0
  const int xcd = blockIdx.x & 7;
  const int local = blockIdx.x >> 3;
  const int nPerX = ntile >> 3;
  const int nt_ = xcd * nPerX + local / mtile;
  const int mt_ = local % mtile;
  const int m0 = mt_ * 128, n0 = nt_ * 128;

  const int srow = lane >> 3;
  const int scol = (lane & 7) * 8;

  f32x4 acc[4][4] = {};

#define STAGE_G(buf, kk0)                                                        \
  do {                                                                           \
    _Pragma("unroll")                                                            \
    for (int c = 0; c < 4; ++c) {                                                \
      const int chunk = wave * 4 + c;                                            \
      const int row = chunk * 8 + srow;                                          \
      gload_lds16(A  + (size_t)(m0 + row) * K + (kk0) + scol,                    \
                  &As[buf][chunk * 512 + lane * 8]);                             \
      gload_lds16(BT + (size_t)(n0 + row) * K + (kk0) + scol,                    \
                  &Bs[buf][chunk * 512 + lane * 8]);                             \
    }                                                                            \
  } while (0)

  STAGE_G(0, 0);
  __syncthreads();   // compiler drains vmcnt before barrier

  const int NT = K >> 6;
  for (int t = 0; t < NT; ++t) {
    const int cur = t & 1;
    if (t + 1 < NT) STAGE_G(cur ^ 1, (t + 1) << 6);   // overlap next-tile loads
#pragma unroll
    for (int kk = 0; kk < 2; ++kk) {
      const int ko = kk * 32 + l4 * 8;
      bf16x8 a[4], b[4];
#pragma unroll
      for (int mi = 0; mi < 4; ++mi)
        a[mi] = *(const bf16x8*)&As[cur][(wr + mi * 16 + l15) * 64 + ko];
#pragma unroll
      for (int ni = 0; ni < 4; ++ni)
        b[ni] = *(const bf16x8*)&Bs[cur][(wc + ni * 16 + l15) * 64 + ko];
#pragma unroll
      for (int mi = 0; mi < 4; ++mi)
#pragma unroll
        for (int ni = 0; ni < 4; ++ni)
          acc[mi][ni] = __builtin_amdgcn_mfma_f32_16x16x32_bf16(a[mi], b[ni], acc[mi][ni], 0, 0, 0);
    }
    __syncthreads();   // one barrier per K-step (drains this step's stage)
  }
#undef STAGE_G

#pragma unroll
  for (int mi = 0; mi < 4; ++mi)
#pragma unroll
    for (int ni = 0; ni < 4; ++ni)
#pragma unroll
      for (int r = 0; r < 4; ++r) {
        int row = m0 + wr + mi * 16 + l4 * 4 + r;
        int col = n0 + wc + ni * 16 + l15;
        float val = acc[mi][ni][r];
        if (OUT_BF16) ((ushort*)Cp)[(size_t)row * N + col] = f2bf(val);
        else          ((float*)Cp)[(size_t)row * N + col]  = val;
      }
}

// ---------------------------------------------------------------------------
// RoPE in place on bf16 buffer: element (b,s,h,j) at buf[(b*S+s)*ld + h*HD + j]
// ---------------------------------------------------------------------------
__global__ __launch_bounds__(256)
void rope_kernel(ushort* buf, const int* __restrict__ pos_ids, int nh, int ld, int total) {
  int t = blockIdx.x * 256 + threadIdx.x;
  if (t >= total) return;
  int j = t & 63;
  int rest = t >> 6;
  int h = rest % nh;
  int bs = rest / nh;
  float pos = (float)pos_ids[bs];
  float inv = exp2f(-(float)j * (13.287712379549449f / 64.0f));
  float ang = pos * inv;
  float c = cosf(ang), s = sinf(ang);
  ushort* p = buf + (size_t)bs * ld + h * HD + j;
  float x1 = bf2f(p[0]), x2 = bf2f(p[64]);
  p[0]  = f2bf(x1 * c - x2 * s);
  p[64] = f2bf(x2 * c + x1 * s);
}

// ---------------------------------------------------------------------------
// Flash attention, causal, GQA-shared K/V, async-staged (T14), defer-max (T13).
// Block = (32 q-rows) x (one KV group = 4 heads); wave w handles head kh*4+w.
// ---------------------------------------------------------------------------
__global__ __launch_bounds__(256)
void attn_kernel(const ushort* __restrict__ Q, const ushort* __restrict__ K0,
                 const ushort* __restrict__ V0, ushort* __restrict__ AO) {
  __shared__ ushort Ks[64 * 128];       // [k][d], chunk^=(k&7) swizzled, 16KB
  __shared__ ushort Vs[2][128 * 64];    // [d][k], chunk^=(d&7) swizzled, 2x16KB
  __shared__ ushort Ps[4][32 * 72];     // per-wave P tile 32x64, pad 72

  const int raw  = blockIdx.x;
  const int kh   = raw & 7;             // kv-head -> XCD (L2-resident K/V)
  const int rest = raw >> 3;
  const int qt   = 63 - (rest & 63);    // longest blocks first (LPT)
  const int b    = rest >> 6;
  const int q0   = qt * 32;

  const int tid = threadIdx.x, lane = tid & 63, wave = tid >> 6;
  const int l15 = lane & 15, l4 = lane >> 4;
  const int h = kh * 4 + wave;
  const float SCL2 = 0.1275173110f;     // (1/sqrt(128)) * log2(e)

  const size_t bS = (size_t)b * SEQ;
  const ushort* Kb = K0 + bS * QKVLD + kh * HD;
  const ushort* Vb = V0 + bS * QKVLD + kh * HD;

  // ---- Q fragments: 32 rows x 128 d per wave ----
  bf16x8 qf[2][4];
#pragma unroll
  for (int mi = 0; mi < 2; ++mi) {
    const ushort* qp = Q + (bS + q0 + mi * 16 + l15) * QKVLD + h * HD + l4 * 8;
#pragma unroll
    for (int kk = 0; kk < 4; ++kk) qf[mi][kk] = *(const bf16x8*)(qp + kk * 32);
  }

  float mrow[2][4], denom[2][4];
#pragma unroll
  for (int mi = 0; mi < 2; ++mi)
#pragma unroll
    for (int r = 0; r < 4; ++r) { mrow[mi][r] = -1e30f; denom[mi][r] = 0.0f; }
  f32x4 accO[2][8] = {};

  const int rp0 = tid & 31,        dc0 = tid >> 5;
  const int rp1 = (256 + tid) & 31, dc1 = (256 + tid) >> 5;

  const int nt = qt / 2 + 1;  // causal coverage

  // ---- prologue: stage K(0) and V(0) ----
  {
#pragma unroll
    for (int c = 0; c < 4; ++c) {
      const int j = wave * 4 + c;
      const int row = j * 4 + l4;
      const int chunk = (lane & 15) ^ (row & 7);
      gload_lds16(Kb + (size_t)row * QKVLD + chunk * 8, &Ks[j * 512 + lane * 8]);
    }
    const ushort* vp0 = Vb + (size_t)(2 * rp0) * QKVLD + dc0 * 8;
    const ushort* vp1 = Vb + (size_t)(2 * rp1) * QKVLD + dc1 * 8;
    bf16x8 lo0 = *(const bf16x8*)vp0, hi0 = *(const bf16x8*)(vp0 + QKVLD);
    bf16x8 lo1 = *(const bf16x8*)vp1, hi1 = *(const bf16x8*)(vp1 + QKVLD);
#pragma unroll
    for (int j = 0; j < 8; ++j) {
      const int d0 = dc0 * 8 + j, d1 = dc1 * 8 + j;
      uint v0p = (uint)(ushort)lo0[j] | ((uint)(ushort)hi0[j] << 16);
      uint v1p = (uint)(ushort)lo1[j] | ((uint)(ushort)hi1[j] << 16);
      *(uint*)&Vs[0][d0 * 64 + (((rp0 >> 2) ^ (d0 & 7)) << 3) + ((rp0 & 3) << 1)] = v0p;
      *(uint*)&Vs[0][d1 * 64 + (((rp1 >> 2) ^ (d1 & 7)) << 3) + ((rp1 & 3) << 1)] = v1p;
    }
  }
  __syncthreads();

  for (int t = 0; t < nt; ++t) {
    const int k0 = t * 64;
    const int cur = t & 1;
    const bool mask_tile = (t == nt - 1);
    const bool pf = (t + 1 < nt);

    // ---- QK^T ----
    f32x4 accS[2][4] = {};
    __builtin_amdgcn_s_setprio(1);
#pragma unroll
    for (int kk = 0; kk < 4; ++kk) {
#pragma unroll
      for (int ni = 0; ni < 4; ++ni) {
        bf16x8 kf = *(const bf16x8*)&Ks[(ni * 16 + l15) * 128 +
                                        (((kk * 4 + l4) ^ (l15 & 7)) << 3)];
        accS[0][ni] = __builtin_amdgcn_mfma_f32_16x16x32_bf16(qf[0][kk], kf, accS[0][ni], 0, 0, 0);
        accS[1][ni] = __builtin_amdgcn_mfma_f32_16x16x32_bf16(qf[1][kk], kf, accS[1][ni], 0, 0, 0);
      }
    }
    __builtin_amdgcn_s_setprio(0);
    __syncthreads();   // all waves done reading Ks

    // ---- issue next tile's loads (hide under softmax+PV) ----
    bf16x8 lo0, hi0, lo1, hi1;
    if (pf) {
      const int kn = k0 + 64;
#pragma unroll
      for (int c = 0; c < 4; ++c) {
        const int j = wave * 4 + c;
        const int row = j * 4 + l4;
        const int chunk = (lane & 15) ^ (row & 7);
        gload_lds16(Kb + (size_t)(kn + row) * QKVLD + chunk * 8, &Ks[j * 512 + lane * 8]);
      }
      const ushort* vp0 = Vb + (size_t)(kn + 2 * rp0) * QKVLD + dc0 * 8;
      const ushort* vp1 = Vb + (size_t)(kn + 2 * rp1) * QKVLD + dc1 * 8;
      lo0 = *(const bf16x8*)vp0; hi0 = *(const bf16x8*)(vp0 + QKVLD);
      lo1 = *(const bf16x8*)vp1; hi1 = *(const bf16x8*)(vp1 + QKVLD);
    }

    // ---- softmax (defer-max, per-lane partial denom) ----
    float pmax[2][4];
#pragma unroll
    for (int mi = 0; mi < 2; ++mi)
#pragma unroll
      for (int r = 0; r < 4; ++r) {
        float mx = -3e38f;
#pragma unroll
        for (int ni = 0; ni < 4; ++ni) {
          float x = accS[mi][ni][r] * SCL2;
          if (mask_tile) {
            int kq = k0 + ni * 16 + l15;
            int qq = q0 + mi * 16 + l4 * 4 + r;
            if (kq > qq) x = -1e30f;
          }
          accS[mi][ni][r] = x;
          mx = fmaxf(mx, x);
        }
        pmax[mi][r] = mx;
      }
#pragma unroll
    for (int d = 1; d < 16; d <<= 1)
#pragma unroll
      for (int mi = 0; mi < 2; ++mi)
#pragma unroll
        for (int r = 0; r < 4; ++r)
          pmax[mi][r] = fmaxf(pmax[mi][r], __shfl_xor(pmax[mi][r], d));

    bool ok = true;
#pragma unroll
    for (int mi = 0; mi < 2; ++mi)
#pragma unroll
      for (int r = 0; r < 4; ++r)
        ok = ok && (pmax[mi][r] - mrow[mi][r] <= 8.0f);

    if (__all(ok)) {
#pragma unroll
      for (int mi = 0; mi < 2; ++mi)
#pragma unroll
        for (int r = 0; r < 4; ++r) {
          const float mn = mrow[mi][r];
          float s = 0.0f;
#pragma unroll
          for (int ni = 0; ni < 4; ++ni) {
            float p = exp2f(accS[mi][ni][r] - mn);
            accS[mi][ni][r] = p;
            s += p;
          }
          denom[mi][r] += s;
        }
    } else {
#pragma unroll
      for (int mi = 0; mi < 2; ++mi)
#pragma unroll
        for (int r = 0; r < 4; ++r) {
          const float mn = fmaxf(mrow[mi][r], pmax[mi][r]);
          const float alpha = exp2f(mrow[mi][r] - mn);
          mrow[mi][r] = mn;
          float s = 0.0f;
#pragma unroll
          for (int ni = 0; ni < 4; ++ni) {
            float p = exp2f(accS[mi][ni][r] - mn);
            accS[mi][ni][r] = p;
            s += p;
          }
          denom[mi][r] = denom[mi][r] * alpha + s;
#pragma unroll
          for (int db = 0; db < 8; ++db) accO[mi][db][r] *= alpha;
        }
    }

    // ---- write P to per-wave LDS tile ----
#pragma unroll
    for (int mi = 0; mi < 2; ++mi)
#pragma unroll
      for (int ni = 0; ni < 4; ++ni)
#pragma unroll
        for (int r = 0; r < 4; ++r)
          Ps[wave][(mi * 16 + l4 * 4 + r) * 72 + ni * 16 + l15] = f2bf(accS[mi][ni][r]);

    // ---- PV ----
    __builtin_amdgcn_s_setprio(1);
#pragma unroll
    for (int kk = 0; kk < 2; ++kk) {
      bf16x8 pa[2];
#pragma unroll
      for (int mi = 0; mi < 2; ++mi)
        pa[mi] = *(const bf16x8*)&Ps[wave][(mi * 16 + l15) * 72 + kk * 32 + l4 * 8];
#pragma unroll
      for (int db = 0; db < 8; ++db) {
        bf16x8 vb = *(const bf16x8*)&Vs[cur][(db * 16 + l15) * 64 +
                                            (((kk * 4 + l4) ^ (l15 & 7)) << 3)];
        accO[0][db] = __builtin_amdgcn_mfma_f32_16x16x32_bf16(pa[0], vb, accO[0][db], 0, 0, 0);
        accO[1][db] = __builtin_amdgcn_mfma_f32_16x16x32_bf16(pa[1], vb, accO[1][db], 0, 0, 0);
      }
    }
    __builtin_amdgcn_s_setprio(0);

    // ---- write V(t+1) into other buffer ----
    if (pf) {
#pragma unroll
      for (int j = 0; j < 8; ++j) {
        const int d0 = dc0 * 8 + j, d1 = dc1 * 8 + j;
        uint v0p = (uint)(ushort)lo0[j] | ((uint)(ushort)hi0[j] << 16);
        uint v1p = (uint)(ushort)lo1[j] | ((uint)(ushort)hi1[j] << 16);
        *(uint*)&Vs[cur ^ 1][d0 * 64 + (((rp0 >> 2) ^ (d0 & 7)) << 3) + ((rp0 & 3) << 1)] = v0p;
        *(uint*)&Vs[cur ^ 1][d1 * 64 + (((rp1 >> 2) ^ (d1 & 7)) << 3) + ((rp1 & 3) << 1)] = v1p;
      }
    }
    __syncthreads();
  }

  // ---- epilogue ----
#pragma unroll
  for (int d = 1; d < 16; d <<= 1)
#pragma unroll
    for (int mi = 0; mi < 2; ++mi)
#pragma unroll
      for (int r = 0; r < 4; ++r)
        denom[mi][r] += __shfl_xor(denom[mi][r], d);

#pragma unroll
  for (int mi = 0; mi < 2; ++mi)
#pragma unroll
    for (int db = 0; db < 8; ++db)
#pragma unroll
      for (int r = 0; r < 4; ++r) {
        int q = q0 + mi * 16 + l4 * 4 + r;
        int col = h * HD + db * 16 + l15;
        AO[(bS + q) * HIDDEN + col] = f2bf(accO[mi][db][r] / denom[mi][r]);
      }
}

// ---------------------------------------------------------------------------
extern "C" void kernel_launch(void* const* d_in, const int* in_sizes, int n_in,
                              void* d_out, int out_size, void* d_ws, size_t ws_size,
                              hipStream_t stream) {
  (void)in_sizes; (void)n_in; (void)out_size; (void)ws_size;
  const float* X   = (const float*)d_in[0];
  const int*   pos = (const int*)d_in[2];
  const float* Wq  = (const float*)d_in[3];
  const float* Wk  = (const float*)d_in[4];
  const float* Wv  = (const float*)d_in[5];
  const float* Wo  = (const float*)d_in[6];

  char* ws = (char*)d_ws;
  ushort* Xb    = (ushort*)(ws);                    // 33,554,432 B (aliased by AO)
  ushort* QKV   = (ushort*)(ws + 33554432);         // 50,331,648 B  [M][6144]
  ushort* BTqkv = (ushort*)(ws + 83886080);         // 50,331,648 B  [6144][4096]
  ushort* WoT   = (ushort*)(ws + 134217728);        // 33,554,432 B
  ushort* AO    = Xb;                               // X dead after QKV projection

  const int M = BSZ * SEQ;  // 4096
  dim3 blk(256);

  // ---- pre-passes ----
  cvt_bf16_kernel<<<dim3((M * HIDDEN / 8 + 255) / 256), blk, 0, stream>>>(X, Xb, M * HIDDEN / 8);
  transpose_bf16_kernel<<<dim3(HIDDEN / 32, HIDDEN / 32), blk, 0, stream>>>(Wq, BTqkv, HIDDEN, HIDDEN);
  transpose_bf16_kernel<<<dim3((NKV * HD) / 32, HIDDEN / 32), blk, 0, stream>>>(
      Wk, BTqkv + (size_t)HIDDEN * HIDDEN, HIDDEN, NKV * HD);
  transpose_bf16_kernel<<<dim3((NKV * HD) / 32, HIDDEN / 32), blk, 0, stream>>>(
      Wv, BTqkv + (size_t)(HIDDEN + NKV * HD) * HIDDEN, HIDDEN, NKV * HD);
  transpose_bf16_kernel<<<dim3(HIDDEN / 32, HIDDEN / 32), blk, 0, stream>>>(Wo, WoT, HIDDEN, HIDDEN);

  // ---- fused QKV projection ----
  gemm_bf16_kernel<1><<<dim3((M / 128) * (QKVN / 128)), blk, 0, stream>>>(Xb, BTqkv, QKV, M, QKVN, HIDDEN);

  // ---- RoPE in place ----
  rope_kernel<<<dim3((M * NH * 64) / 256), blk, 0, stream>>>(QKV, pos, NH, QKVLD, M * NH * 64);
  rope_kernel<<<dim3((M * NKV * 64) / 256), blk, 0, stream>>>(QKV + HIDDEN, pos, NKV, QKVLD, M * NKV * 64);

  // ---- flash attention ----
  attn_kernel<<<dim3(8 * 64 * BSZ), blk, 0, stream>>>(
      QKV, QKV + HIDDEN, QKV + HIDDEN + NKV * HD, AO);

  // ---- output projection -> fp32 d_out ----
  gemm_bf16_kernel<0><<<dim3((M / 128) * (HIDDEN / 128)), blk, 0, stream>>>(AO, WoT, d_out, M, HIDDEN, HIDDEN);
}

// Round 6
// 694.373 us; speedup vs baseline: 1.2294x; 1.2294x over previous
//
#include <hip/hip_runtime.h>
#include <hip/hip_bf16.h>
#include <cstdint>

#define HIDDEN 4096
#define NH 32
#define NKV 8
#define HD 128
#define SEQ 2048
#define BSZ 2
#define QKVN 6144          // fused QKV projection width
#define QKVLD 6144         // row stride of fused QKV buffer

using bf16x8 = __attribute__((ext_vector_type(8))) short;
using f32x4  = __attribute__((ext_vector_type(4))) float;

__device__ __forceinline__ ushort f2bf(float f) {
  union { float f; uint32_t u; } v; v.f = f;
  uint32_t r = (v.u + 0x7FFFu + ((v.u >> 16) & 1u)) >> 16;  // RNE
  return (ushort)r;
}
__device__ __forceinline__ float bf2f(ushort s) {
  union { uint32_t u; float f; } v; v.u = ((uint32_t)s) << 16;
  return v.f;
}

__device__ __forceinline__ void gload_lds16(const void* g, void* l) {
  __builtin_amdgcn_global_load_lds(
      (const __attribute__((address_space(1))) void*)g,
      (__attribute__((address_space(3))) void*)l, 16, 0, 0);
}

// ---------------------------------------------------------------------------
// fp32 -> bf16 elementwise convert (vectorized, 8 elems/thread)
// ---------------------------------------------------------------------------
__global__ __launch_bounds__(256)
void cvt_bf16_kernel(const float* __restrict__ X, ushort* __restrict__ Xb, int n8) {
  int t = blockIdx.x * 256 + threadIdx.x;
  if (t >= n8) return;
  size_t i = (size_t)t * 8;
  float4 a = *(const float4*)(X + i);
  float4 b = *(const float4*)(X + i + 4);
  uint4 p;
  p.x = (uint)f2bf(a.x) | ((uint)f2bf(a.y) << 16);
  p.y = (uint)f2bf(a.z) | ((uint)f2bf(a.w) << 16);
  p.z = (uint)f2bf(b.x) | ((uint)f2bf(b.y) << 16);
  p.w = (uint)f2bf(b.z) | ((uint)f2bf(b.w) << 16);
  *(uint4*)(Xb + i) = p;
}

// ---------------------------------------------------------------------------
// W[K][N] fp32 -> WT[N][K] bf16 (32x32 LDS tile transpose)
// ---------------------------------------------------------------------------
__global__ __launch_bounds__(256)
void transpose_bf16_kernel(const float* __restrict__ W, ushort* __restrict__ WT,
                           int K, int N) {
  __shared__ ushort tile[32][33];
  const int k0 = blockIdx.y * 32, n0 = blockIdx.x * 32;
  const int tx = threadIdx.x & 31, ty = threadIdx.x >> 5;  // ty 0..7
  for (int i = 0; i < 4; ++i) {
    int k = ty + i * 8;
    tile[k][tx] = f2bf(W[(size_t)(k0 + k) * N + n0 + tx]);
  }
  __syncthreads();
  for (int i = 0; i < 4; ++i) {
    int n = ty + i * 8;
    WT[(size_t)(n0 + n) * K + k0 + tx] = tile[tx][n];
  }
}

// ---------------------------------------------------------------------------
// 256x256 8-phase GEMM: C[MxN] = A[MxK] * BT[NxK]^T, bf16 inputs.
// 8 waves (2Mx4N), BK=64, 128KB dynamic LDS (2buf x 2op x 2kslice x 16KB),
// counted vmcnt(8) (never 0 in main loop), raw s_barrier (no vmcnt drain),
// kslice XOR-swizzle (slot ^= (row>>1)&3) via pre-swizzled global source,
// setprio around MFMA clusters, bijective XCD swizzle (m-fastest).
// ---------------------------------------------------------------------------
template<int OUT_BF16>
__global__ __launch_bounds__(512, 2)
void gemm8p_kernel(const ushort* __restrict__ A, const ushort* __restrict__ BT,
                   void* __restrict__ Cp, int M, int N, int K) {
  extern __shared__ ushort lds[];   // 128 KB
  const int tid = threadIdx.x, lane = tid & 63, wave = tid >> 6;
  const int l15 = lane & 15, l4 = lane >> 4;
  const int wr = wave >> 2, wc = wave & 3;

  // bijective XCD-chunked swizzle (m204), m-fastest within chunk
  const int mt = M >> 8, nt = N >> 8, nwg = mt * nt;
  const int swq = nwg >> 3, swr = nwg & 7;
  const int xcd = blockIdx.x & 7, lo = blockIdx.x >> 3;
  const int wg = (xcd < swr ? xcd * (swq + 1) : swr * (swq + 1) + (xcd - swr) * swq) + lo;
  const int m0 = (wg % mt) << 8;
  const int n0 = (wg / mt) << 8;

  // LDS regions: [buf][op][ks] each 8192 ushorts (16KB)
  ushort* LA[2][2];
  ushort* LB[2][2];
#pragma unroll
  for (int b_ = 0; b_ < 2; ++b_)
#pragma unroll
    for (int s_ = 0; s_ < 2; ++s_) {
      LA[b_][s_] = lds + ((b_ * 2 + 0) * 2 + s_) * 8192;
      LB[b_][s_] = lds + ((b_ * 2 + 1) * 2 + s_) * 8192;
    }

  const ushort* Abase = A + (size_t)m0 * K;
  const ushort* Bbase = BT + (size_t)n0 * K;

  // staging geometry: idx = part*512 + tid; row = idx>>2; slot = tid&3
  const int srow0 = tid >> 2;                                  // part-0 row
  const int scol8 = (((tid & 3) ^ ((srow0 >> 1) & 3)) << 3);   // swizzled src col (elems)

  // read-side swizzle: lane-constant 16B slot
  const int swb  = (l4 ^ ((l15 >> 1) & 3)) << 3;               // ushort offset
  const int aoff = (wr * 128 + l15) * 32 + swb;                // + m*512
  const int boff = (wc * 64 + l15) * 32 + swb;                 // + n*512

  f32x4 acc[8][4] = {};
  bf16x8 a[8];
  bf16x8 b[4];

#define STAGE(buf, ks, kt, part)                                              \
  do {                                                                        \
    const size_t gc_ = (size_t)(kt) * 64 + (ks) * 32 + scol8;                 \
    const int rw_ = srow0 + (part) * 128;                                     \
    const int dst_ = ((part) * 512 + tid) * 8;                                \
    gload_lds16(Abase + (size_t)rw_ * K + gc_, &LA[buf][ks][dst_]);           \
    gload_lds16(Bbase + (size_t)rw_ * K + gc_, &LB[buf][ks][dst_]);           \
  } while (0)

#define MFMA_ __builtin_amdgcn_mfma_f32_16x16x32_bf16

#define PHASE_EVEN(buf, ks, sb, sk, skt)                                      \
  {                                                                           \
    _Pragma("unroll") for (int m_ = 0; m_ < 8; ++m_)                          \
      a[m_] = *(const bf16x8*)&LA[buf][ks][aoff + m_ * 512];                  \
    b[0] = *(const bf16x8*)&LB[buf][ks][boff];                                \
    b[1] = *(const bf16x8*)&LB[buf][ks][boff + 512];                          \
    STAGE(sb, sk, skt, 0);                                                    \
    asm volatile("s_barrier" ::: "memory");                                   \
    __builtin_amdgcn_s_setprio(1);                                            \
    _Pragma("unroll") for (int m_ = 0; m_ < 8; ++m_) {                        \
      acc[m_][0] = MFMA_(a[m_], b[0], acc[m_][0], 0, 0, 0);                   \
      acc[m_][1] = MFMA_(a[m_], b[1], acc[m_][1], 0, 0, 0);                   \
    }                                                                         \
    __builtin_amdgcn_s_setprio(0);                                            \
    asm volatile("s_barrier" ::: "memory");                                   \
  }

#define PHASE_ODD(buf, ks, sb, sk, skt)                                       \
  {                                                                           \
    b[2] = *(const bf16x8*)&LB[buf][ks][boff + 1024];                         \
    b[3] = *(const bf16x8*)&LB[buf][ks][boff + 1536];                         \
    STAGE(sb, sk, skt, 1);                                                    \
    asm volatile("s_barrier" ::: "memory");                                   \
    __builtin_amdgcn_s_setprio(1);                                            \
    _Pragma("unroll") for (int m_ = 0; m_ < 8; ++m_) {                        \
      acc[m_][2] = MFMA_(a[m_], b[2], acc[m_][2], 0, 0, 0);                   \
      acc[m_][3] = MFMA_(a[m_], b[3], acc[m_][3], 0, 0, 0);                   \
    }                                                                         \
    __builtin_amdgcn_s_setprio(0);                                            \
    asm volatile("s_waitcnt vmcnt(8)");                                       \
    asm volatile("s_barrier" ::: "memory");                                   \
  }

  const int NT = K >> 6;   // ktiles (even: 64 or 96... here 64)

  // ---- prologue: stage buf0.ks0, buf0.ks1 (ktile0), buf1.ks0 (ktile1) ----
  STAGE(0, 0, 0, 0); STAGE(0, 0, 0, 1);
  STAGE(0, 1, 0, 0); STAGE(0, 1, 0, 1);
  STAGE(1, 0, 1, 0); STAGE(1, 0, 1, 1);
  asm volatile("s_waitcnt vmcnt(8)");    // buf0.ks0 landed
  asm volatile("s_barrier" ::: "memory");

  for (int i = 0; i < (NT >> 1); ++i) {
    const int kt0 = 2 * i;
    const int ktA = (kt0 + 2 < NT) ? kt0 + 2 : NT - 1;  // clamp keeps vmcnt uniform
    const int ktB = (kt0 + 3 < NT) ? kt0 + 3 : NT - 1;
    PHASE_EVEN(0, 0, 1, 1, kt0 + 1)
    PHASE_ODD (0, 0, 1, 1, kt0 + 1)
    PHASE_EVEN(0, 1, 0, 0, ktA)
    PHASE_ODD (0, 1, 0, 0, ktA)
    PHASE_EVEN(1, 0, 0, 1, ktA)
    PHASE_ODD (1, 0, 0, 1, ktA)
    PHASE_EVEN(1, 1, 1, 0, ktB)
    PHASE_ODD (1, 1, 1, 0, ktB)
  }
#undef PHASE_EVEN
#undef PHASE_ODD
#undef STAGE

  // ---- epilogue: D row=(l4*4+r), col=l15 within each 16x16 frag ----
  const int crow0 = m0 + wr * 128 + l4 * 4;
  const int ccol0 = n0 + wc * 64 + l15;
#pragma unroll
  for (int m_ = 0; m_ < 8; ++m_)
#pragma unroll
    for (int n_ = 0; n_ < 4; ++n_)
#pragma unroll
      for (int r_ = 0; r_ < 4; ++r_) {
        const size_t row = crow0 + m_ * 16 + r_;
        const int col = ccol0 + n_ * 16;
        const float val = acc[m_][n_][r_];
        if (OUT_BF16) ((ushort*)Cp)[row * N + col] = f2bf(val);
        else          ((float*)Cp)[row * N + col]  = val;
      }
}

// ---------------------------------------------------------------------------
// RoPE in place on bf16 buffer: element (b,s,h,j) at buf[(b*S+s)*ld + h*HD + j]
// ---------------------------------------------------------------------------
__global__ __launch_bounds__(256)
void rope_kernel(ushort* buf, const int* __restrict__ pos_ids, int nh, int ld, int total) {
  int t = blockIdx.x * 256 + threadIdx.x;
  if (t >= total) return;
  int j = t & 63;
  int rest = t >> 6;
  int h = rest % nh;
  int bs = rest / nh;
  float pos = (float)pos_ids[bs];
  float inv = exp2f(-(float)j * (13.287712379549449f / 64.0f));
  float ang = pos * inv;
  float c = cosf(ang), s = sinf(ang);
  ushort* p = buf + (size_t)bs * ld + h * HD + j;
  float x1 = bf2f(p[0]), x2 = bf2f(p[64]);
  p[0]  = f2bf(x1 * c - x2 * s);
  p[64] = f2bf(x2 * c + x1 * s);
}

// ---------------------------------------------------------------------------
// Flash attention, causal, GQA-shared K/V, async-staged (T14), defer-max (T13).
// Block = (32 q-rows) x (one KV group = 4 heads); wave w handles head kh*4+w.
// ---------------------------------------------------------------------------
__global__ __launch_bounds__(256)
void attn_kernel(const ushort* __restrict__ Q, const ushort* __restrict__ K0,
                 const ushort* __restrict__ V0, ushort* __restrict__ AO) {
  __shared__ ushort Ks[64 * 128];       // [k][d], chunk^=(k&7) swizzled, 16KB
  __shared__ ushort Vs[2][128 * 64];    // [d][k], chunk^=(d&7) swizzled, 2x16KB
  __shared__ ushort Ps[4][32 * 72];     // per-wave P tile 32x64, pad 72

  const int raw  = blockIdx.x;
  const int kh   = raw & 7;             // kv-head -> XCD (L2-resident K/V)
  const int rest = raw >> 3;
  const int qt   = 63 - (rest & 63);    // longest blocks first (LPT)
  const int b    = rest >> 6;
  const int q0   = qt * 32;

  const int tid = threadIdx.x, lane = tid & 63, wave = tid >> 6;
  const int l15 = lane & 15, l4 = lane >> 4;
  const int h = kh * 4 + wave;
  const float SCL2 = 0.1275173110f;     // (1/sqrt(128)) * log2(e)

  const size_t bS = (size_t)b * SEQ;
  const ushort* Kb = K0 + bS * QKVLD + kh * HD;
  const ushort* Vb = V0 + bS * QKVLD + kh * HD;

  // ---- Q fragments: 32 rows x 128 d per wave ----
  bf16x8 qf[2][4];
#pragma unroll
  for (int mi = 0; mi < 2; ++mi) {
    const ushort* qp = Q + (bS + q0 + mi * 16 + l15) * QKVLD + h * HD + l4 * 8;
#pragma unroll
    for (int kk = 0; kk < 4; ++kk) qf[mi][kk] = *(const bf16x8*)(qp + kk * 32);
  }

  float mrow[2][4], denom[2][4];
#pragma unroll
  for (int mi = 0; mi < 2; ++mi)
#pragma unroll
    for (int r = 0; r < 4; ++r) { mrow[mi][r] = -1e30f; denom[mi][r] = 0.0f; }
  f32x4 accO[2][8] = {};

  const int rp0 = tid & 31,        dc0 = tid >> 5;
  const int rp1 = (256 + tid) & 31, dc1 = (256 + tid) >> 5;

  const int nt = qt / 2 + 1;  // causal coverage

  // ---- prologue: stage K(0) and V(0) ----
  {
#pragma unroll
    for (int c = 0; c < 4; ++c) {
      const int j = wave * 4 + c;
      const int row = j * 4 + l4;
      const int chunk = (lane & 15) ^ (row & 7);
      gload_lds16(Kb + (size_t)row * QKVLD + chunk * 8, &Ks[j * 512 + lane * 8]);
    }
    const ushort* vp0 = Vb + (size_t)(2 * rp0) * QKVLD + dc0 * 8;
    const ushort* vp1 = Vb + (size_t)(2 * rp1) * QKVLD + dc1 * 8;
    bf16x8 lo0 = *(const bf16x8*)vp0, hi0 = *(const bf16x8*)(vp0 + QKVLD);
    bf16x8 lo1 = *(const bf16x8*)vp1, hi1 = *(const bf16x8*)(vp1 + QKVLD);
#pragma unroll
    for (int j = 0; j < 8; ++j) {
      const int d0 = dc0 * 8 + j, d1 = dc1 * 8 + j;
      uint v0p = (uint)(ushort)lo0[j] | ((uint)(ushort)hi0[j] << 16);
      uint v1p = (uint)(ushort)lo1[j] | ((uint)(ushort)hi1[j] << 16);
      *(uint*)&Vs[0][d0 * 64 + (((rp0 >> 2) ^ (d0 & 7)) << 3) + ((rp0 & 3) << 1)] = v0p;
      *(uint*)&Vs[0][d1 * 64 + (((rp1 >> 2) ^ (d1 & 7)) << 3) + ((rp1 & 3) << 1)] = v1p;
    }
  }
  __syncthreads();

  for (int t = 0; t < nt; ++t) {
    const int k0 = t * 64;
    const int cur = t & 1;
    const bool mask_tile = (t == nt - 1);
    const bool pf = (t + 1 < nt);

    // ---- QK^T ----
    f32x4 accS[2][4] = {};
    __builtin_amdgcn_s_setprio(1);
#pragma unroll
    for (int kk = 0; kk < 4; ++kk) {
#pragma unroll
      for (int ni = 0; ni < 4; ++ni) {
        bf16x8 kf = *(const bf16x8*)&Ks[(ni * 16 + l15) * 128 +
                                        (((kk * 4 + l4) ^ (l15 & 7)) << 3)];
        accS[0][ni] = __builtin_amdgcn_mfma_f32_16x16x32_bf16(qf[0][kk], kf, accS[0][ni], 0, 0, 0);
        accS[1][ni] = __builtin_amdgcn_mfma_f32_16x16x32_bf16(qf[1][kk], kf, accS[1][ni], 0, 0, 0);
      }
    }
    __builtin_amdgcn_s_setprio(0);
    __syncthreads();   // all waves done reading Ks

    // ---- issue next tile's loads (hide under softmax+PV) ----
    bf16x8 lo0, hi0, lo1, hi1;
    if (pf) {
      const int kn = k0 + 64;
#pragma unroll
      for (int c = 0; c < 4; ++c) {
        const int j = wave * 4 + c;
        const int row = j * 4 + l4;
        const int chunk = (lane & 15) ^ (row & 7);
        gload_lds16(Kb + (size_t)(kn + row) * QKVLD + chunk * 8, &Ks[j * 512 + lane * 8]);
      }
      const ushort* vp0 = Vb + (size_t)(kn + 2 * rp0) * QKVLD + dc0 * 8;
      const ushort* vp1 = Vb + (size_t)(kn + 2 * rp1) * QKVLD + dc1 * 8;
      lo0 = *(const bf16x8*)vp0; hi0 = *(const bf16x8*)(vp0 + QKVLD);
      lo1 = *(const bf16x8*)vp1; hi1 = *(const bf16x8*)(vp1 + QKVLD);
    }

    // ---- softmax (defer-max, per-lane partial denom) ----
    float pmax[2][4];
#pragma unroll
    for (int mi = 0; mi < 2; ++mi)
#pragma unroll
      for (int r = 0; r < 4; ++r) {
        float mx = -3e38f;
#pragma unroll
        for (int ni = 0; ni < 4; ++ni) {
          float x = accS[mi][ni][r] * SCL2;
          if (mask_tile) {
            int kq = k0 + ni * 16 + l15;
            int qq = q0 + mi * 16 + l4 * 4 + r;
            if (kq > qq) x = -1e30f;
          }
          accS[mi][ni][r] = x;
          mx = fmaxf(mx, x);
        }
        pmax[mi][r] = mx;
      }
#pragma unroll
    for (int d = 1; d < 16; d <<= 1)
#pragma unroll
      for (int mi = 0; mi < 2; ++mi)
#pragma unroll
        for (int r = 0; r < 4; ++r)
          pmax[mi][r] = fmaxf(pmax[mi][r], __shfl_xor(pmax[mi][r], d));

    bool ok = true;
#pragma unroll
    for (int mi = 0; mi < 2; ++mi)
#pragma unroll
      for (int r = 0; r < 4; ++r)
        ok = ok && (pmax[mi][r] - mrow[mi][r] <= 8.0f);

    if (__all(ok)) {
#pragma unroll
      for (int mi = 0; mi < 2; ++mi)
#pragma unroll
        for (int r = 0; r < 4; ++r) {
          const float mn = mrow[mi][r];
          float s = 0.0f;
#pragma unroll
          for (int ni = 0; ni < 4; ++ni) {
            float p = exp2f(accS[mi][ni][r] - mn);
            accS[mi][ni][r] = p;
            s += p;
          }
          denom[mi][r] += s;
        }
    } else {
#pragma unroll
      for (int mi = 0; mi < 2; ++mi)
#pragma unroll
        for (int r = 0; r < 4; ++r) {
          const float mn = fmaxf(mrow[mi][r], pmax[mi][r]);
          const float alpha = exp2f(mrow[mi][r] - mn);
          mrow[mi][r] = mn;
          float s = 0.0f;
#pragma unroll
          for (int ni = 0; ni < 4; ++ni) {
            float p = exp2f(accS[mi][ni][r] - mn);
            accS[mi][ni][r] = p;
            s += p;
          }
          denom[mi][r] = denom[mi][r] * alpha + s;
#pragma unroll
          for (int db = 0; db < 8; ++db) accO[mi][db][r] *= alpha;
        }
    }

    // ---- write P to per-wave LDS tile ----
#pragma unroll
    for (int mi = 0; mi < 2; ++mi)
#pragma unroll
      for (int ni = 0; ni < 4; ++ni)
#pragma unroll
        for (int r = 0; r < 4; ++r)
          Ps[wave][(mi * 16 + l4 * 4 + r) * 72 + ni * 16 + l15] = f2bf(accS[mi][ni][r]);

    // ---- PV ----
    __builtin_amdgcn_s_setprio(1);
#pragma unroll
    for (int kk = 0; kk < 2; ++kk) {
      bf16x8 pa[2];
#pragma unroll
      for (int mi = 0; mi < 2; ++mi)
        pa[mi] = *(const bf16x8*)&Ps[wave][(mi * 16 + l15) * 72 + kk * 32 + l4 * 8];
#pragma unroll
      for (int db = 0; db < 8; ++db) {
        bf16x8 vb = *(const bf16x8*)&Vs[cur][(db * 16 + l15) * 64 +
                                            (((kk * 4 + l4) ^ (l15 & 7)) << 3)];
        accO[0][db] = __builtin_amdgcn_mfma_f32_16x16x32_bf16(pa[0], vb, accO[0][db], 0, 0, 0);
        accO[1][db] = __builtin_amdgcn_mfma_f32_16x16x32_bf16(pa[1], vb, accO[1][db], 0, 0, 0);
      }
    }
    __builtin_amdgcn_s_setprio(0);

    // ---- write V(t+1) into other buffer ----
    if (pf) {
#pragma unroll
      for (int j = 0; j < 8; ++j) {
        const int d0 = dc0 * 8 + j, d1 = dc1 * 8 + j;
        uint v0p = (uint)(ushort)lo0[j] | ((uint)(ushort)hi0[j] << 16);
        uint v1p = (uint)(ushort)lo1[j] | ((uint)(ushort)hi1[j] << 16);
        *(uint*)&Vs[cur ^ 1][d0 * 64 + (((rp0 >> 2) ^ (d0 & 7)) << 3) + ((rp0 & 3) << 1)] = v0p;
        *(uint*)&Vs[cur ^ 1][d1 * 64 + (((rp1 >> 2) ^ (d1 & 7)) << 3) + ((rp1 & 3) << 1)] = v1p;
      }
    }
    __syncthreads();
  }

  // ---- epilogue ----
#pragma unroll
  for (int d = 1; d < 16; d <<= 1)
#pragma unroll
    for (int mi = 0; mi < 2; ++mi)
#pragma unroll
      for (int r = 0; r < 4; ++r)
        denom[mi][r] += __shfl_xor(denom[mi][r], d);

#pragma unroll
  for (int mi = 0; mi < 2; ++mi)
#pragma unroll
    for (int db = 0; db < 8; ++db)
#pragma unroll
      for (int r = 0; r < 4; ++r) {
        int q = q0 + mi * 16 + l4 * 4 + r;
        int col = h * HD + db * 16 + l15;
        AO[(bS + q) * HIDDEN + col] = f2bf(accO[mi][db][r] / denom[mi][r]);
      }
}

// ---------------------------------------------------------------------------
extern "C" void kernel_launch(void* const* d_in, const int* in_sizes, int n_in,
                              void* d_out, int out_size, void* d_ws, size_t ws_size,
                              hipStream_t stream) {
  (void)in_sizes; (void)n_in; (void)out_size; (void)ws_size;
  const float* X   = (const float*)d_in[0];
  const int*   pos = (const int*)d_in[2];
  const float* Wq  = (const float*)d_in[3];
  const float* Wk  = (const float*)d_in[4];
  const float* Wv  = (const float*)d_in[5];
  const float* Wo  = (const float*)d_in[6];

  char* ws = (char*)d_ws;
  ushort* Xb    = (ushort*)(ws);                    // 33,554,432 B (aliased by AO)
  ushort* QKV   = (ushort*)(ws + 33554432);         // 50,331,648 B  [M][6144]
  ushort* BTqkv = (ushort*)(ws + 83886080);         // 50,331,648 B  [6144][4096]
  ushort* WoT   = (ushort*)(ws + 134217728);        // 33,554,432 B
  ushort* AO    = Xb;                               // X dead after QKV projection

  const int M = BSZ * SEQ;  // 4096
  dim3 blk(256);

  // allow 128KB dynamic LDS for the 8-phase GEMM (host-side attr, idempotent)
  hipFuncSetAttribute((const void*)gemm8p_kernel<1>,
                      hipFuncAttributeMaxDynamicSharedMemorySize, 131072);
  hipFuncSetAttribute((const void*)gemm8p_kernel<0>,
                      hipFuncAttributeMaxDynamicSharedMemorySize, 131072);

  // ---- pre-passes ----
  cvt_bf16_kernel<<<dim3((M * HIDDEN / 8 + 255) / 256), blk, 0, stream>>>(X, Xb, M * HIDDEN / 8);
  transpose_bf16_kernel<<<dim3(HIDDEN / 32, HIDDEN / 32), blk, 0, stream>>>(Wq, BTqkv, HIDDEN, HIDDEN);
  transpose_bf16_kernel<<<dim3((NKV * HD) / 32, HIDDEN / 32), blk, 0, stream>>>(
      Wk, BTqkv + (size_t)HIDDEN * HIDDEN, HIDDEN, NKV * HD);
  transpose_bf16_kernel<<<dim3((NKV * HD) / 32, HIDDEN / 32), blk, 0, stream>>>(
      Wv, BTqkv + (size_t)(HIDDEN + NKV * HD) * HIDDEN, HIDDEN, NKV * HD);
  transpose_bf16_kernel<<<dim3(HIDDEN / 32, HIDDEN / 32), blk, 0, stream>>>(Wo, WoT, HIDDEN, HIDDEN);

  // ---- fused QKV projection: 16x24 = 384 blocks, 512 thr, 128KB LDS ----
  gemm8p_kernel<1><<<dim3((M / 256) * (QKVN / 256)), dim3(512), 131072, stream>>>(
      Xb, BTqkv, QKV, M, QKVN, HIDDEN);

  // ---- RoPE in place ----
  rope_kernel<<<dim3((M * NH * 64) / 256), blk, 0, stream>>>(QKV, pos, NH, QKVLD, M * NH * 64);
  rope_kernel<<<dim3((M * NKV * 64) / 256), blk, 0, stream>>>(QKV + HIDDEN, pos, NKV, QKVLD, M * NKV * 64);

  // ---- flash attention ----
  attn_kernel<<<dim3(8 * 64 * BSZ), blk, 0, stream>>>(
      QKV, QKV + HIDDEN, QKV + HIDDEN + NKV * HD, AO);

  // ---- output projection -> fp32 d_out: 16x16 = 256 blocks ----
  gemm8p_kernel<0><<<dim3((M / 256) * (HIDDEN / 256)), dim3(512), 131072, stream>>>(
      AO, WoT, d_out, M, HIDDEN, HIDDEN);
}

// Round 7
// 639.071 us; speedup vs baseline: 1.3358x; 1.0865x over previous
//
#include <hip/hip_runtime.h>
#include <hip/hip_bf16.h>
#include <cstdint>

#define HIDDEN 4096
#define NH 32
#define NKV 8
#define HD 128
#define SEQ 2048
#define BSZ 2
#define QKVN 6144          // fused QKV projection width
#define QKVLD 6144         // row stride of fused QKV buffer

using bf16x8 = __attribute__((ext_vector_type(8))) short;
using f32x4  = __attribute__((ext_vector_type(4))) float;

__device__ __forceinline__ ushort f2bf(float f) {
  union { float f; uint32_t u; } v; v.f = f;
  uint32_t r = (v.u + 0x7FFFu + ((v.u >> 16) & 1u)) >> 16;  // RNE
  return (ushort)r;
}
__device__ __forceinline__ float bf2f(ushort s) {
  union { uint32_t u; float f; } v; v.u = ((uint32_t)s) << 16;
  return v.f;
}

__device__ __forceinline__ void gload_lds16(const void* g, void* l) {
  __builtin_amdgcn_global_load_lds(
      (const __attribute__((address_space(1))) void*)g,
      (__attribute__((address_space(3))) void*)l, 16, 0, 0);
}

// ---------------------------------------------------------------------------
// fp32 -> bf16 elementwise convert (vectorized, 8 elems/thread)
// ---------------------------------------------------------------------------
__global__ __launch_bounds__(256)
void cvt_bf16_kernel(const float* __restrict__ X, ushort* __restrict__ Xb, int n8) {
  int t = blockIdx.x * 256 + threadIdx.x;
  if (t >= n8) return;
  size_t i = (size_t)t * 8;
  float4 a = *(const float4*)(X + i);
  float4 b = *(const float4*)(X + i + 4);
  uint4 p;
  p.x = (uint)f2bf(a.x) | ((uint)f2bf(a.y) << 16);
  p.y = (uint)f2bf(a.z) | ((uint)f2bf(a.w) << 16);
  p.z = (uint)f2bf(b.x) | ((uint)f2bf(b.y) << 16);
  p.w = (uint)f2bf(b.z) | ((uint)f2bf(b.w) << 16);
  *(uint4*)(Xb + i) = p;
}

// ---------------------------------------------------------------------------
// W[K][N] fp32 -> WT[N][K] bf16 (32x32 LDS tile transpose)
// ---------------------------------------------------------------------------
__global__ __launch_bounds__(256)
void transpose_bf16_kernel(const float* __restrict__ W, ushort* __restrict__ WT,
                           int K, int N) {
  __shared__ ushort tile[32][33];
  const int k0 = blockIdx.y * 32, n0 = blockIdx.x * 32;
  const int tx = threadIdx.x & 31, ty = threadIdx.x >> 5;  // ty 0..7
  for (int i = 0; i < 4; ++i) {
    int k = ty + i * 8;
    tile[k][tx] = f2bf(W[(size_t)(k0 + k) * N + n0 + tx]);
  }
  __syncthreads();
  for (int i = 0; i < 4; ++i) {
    int n = ty + i * 8;
    WT[(size_t)(n0 + n) * K + k0 + tx] = tile[tx][n];
  }
}

// ---------------------------------------------------------------------------
// V part of QKV -> per-head transposed VtG[(b*NKV+kh)][d=128][SEQ] (bf16)
// ---------------------------------------------------------------------------
__global__ __launch_bounds__(256)
void transpose_v_kernel(const ushort* __restrict__ Vsrc, ushort* __restrict__ VtG) {
  __shared__ ushort tile[32][33];
  const int slice = blockIdx.z;                 // b*NKV + kh
  const int b = slice >> 3, kh = slice & 7;
  const int s0 = blockIdx.x * 32, d0 = blockIdx.y * 32;
  const int tx = threadIdx.x & 31, ty = threadIdx.x >> 5;  // ty 0..7
  const ushort* src = Vsrc + ((size_t)(b * SEQ) + s0) * QKVLD + kh * HD + d0;
  for (int i = 0; i < 4; ++i) {
    int s = ty + i * 8;
    tile[s][tx] = src[(size_t)s * QKVLD + tx];
  }
  __syncthreads();
  ushort* dst = VtG + ((size_t)slice * HD + d0) * SEQ + s0;
  for (int i = 0; i < 4; ++i) {
    int d = ty + i * 8;
    dst[(size_t)d * SEQ + tx] = tile[tx][d];
  }
}

// ---------------------------------------------------------------------------
// 256x256 8-phase GEMM: C[MxN] = A[MxK] * BT[NxK]^T, bf16 inputs.
// ---------------------------------------------------------------------------
template<int OUT_BF16>
__global__ __launch_bounds__(512, 2)
void gemm8p_kernel(const ushort* __restrict__ A, const ushort* __restrict__ BT,
                   void* __restrict__ Cp, int M, int N, int K) {
  extern __shared__ ushort lds[];   // 128 KB
  const int tid = threadIdx.x, lane = tid & 63, wave = tid >> 6;
  const int l15 = lane & 15, l4 = lane >> 4;
  const int wr = wave >> 2, wc = wave & 3;

  // bijective XCD-chunked swizzle (m204), m-fastest within chunk
  const int mt = M >> 8, nt = N >> 8, nwg = mt * nt;
  const int swq = nwg >> 3, swr = nwg & 7;
  const int xcd = blockIdx.x & 7, lo = blockIdx.x >> 3;
  const int wg = (xcd < swr ? xcd * (swq + 1) : swr * (swq + 1) + (xcd - swr) * swq) + lo;
  const int m0 = (wg % mt) << 8;
  const int n0 = (wg / mt) << 8;

  ushort* LA[2][2];
  ushort* LB[2][2];
#pragma unroll
  for (int b_ = 0; b_ < 2; ++b_)
#pragma unroll
    for (int s_ = 0; s_ < 2; ++s_) {
      LA[b_][s_] = lds + ((b_ * 2 + 0) * 2 + s_) * 8192;
      LB[b_][s_] = lds + ((b_ * 2 + 1) * 2 + s_) * 8192;
    }

  const ushort* Abase = A + (size_t)m0 * K;
  const ushort* Bbase = BT + (size_t)n0 * K;

  const int srow0 = tid >> 2;
  const int scol8 = (((tid & 3) ^ ((srow0 >> 1) & 3)) << 3);

  const int swb  = (l4 ^ ((l15 >> 1) & 3)) << 3;
  const int aoff = (wr * 128 + l15) * 32 + swb;
  const int boff = (wc * 64 + l15) * 32 + swb;

  f32x4 acc[8][4] = {};
  bf16x8 a[8];
  bf16x8 b[4];

#define STAGE(buf, ks, kt, part)                                              \
  do {                                                                        \
    const size_t gc_ = (size_t)(kt) * 64 + (ks) * 32 + scol8;                 \
    const int rw_ = srow0 + (part) * 128;                                     \
    const int dst_ = ((part) * 512 + tid) * 8;                                \
    gload_lds16(Abase + (size_t)rw_ * K + gc_, &LA[buf][ks][dst_]);           \
    gload_lds16(Bbase + (size_t)rw_ * K + gc_, &LB[buf][ks][dst_]);           \
  } while (0)

#define MFMA_ __builtin_amdgcn_mfma_f32_16x16x32_bf16

#define PHASE_EVEN(buf, ks, sb, sk, skt)                                      \
  {                                                                           \
    _Pragma("unroll") for (int m_ = 0; m_ < 8; ++m_)                          \
      a[m_] = *(const bf16x8*)&LA[buf][ks][aoff + m_ * 512];                  \
    b[0] = *(const bf16x8*)&LB[buf][ks][boff];                                \
    b[1] = *(const bf16x8*)&LB[buf][ks][boff + 512];                          \
    STAGE(sb, sk, skt, 0);                                                    \
    asm volatile("s_barrier" ::: "memory");                                   \
    __builtin_amdgcn_s_setprio(1);                                            \
    _Pragma("unroll") for (int m_ = 0; m_ < 8; ++m_) {                        \
      acc[m_][0] = MFMA_(a[m_], b[0], acc[m_][0], 0, 0, 0);                   \
      acc[m_][1] = MFMA_(a[m_], b[1], acc[m_][1], 0, 0, 0);                   \
    }                                                                         \
    __builtin_amdgcn_s_setprio(0);                                            \
    asm volatile("s_barrier" ::: "memory");                                   \
  }

#define PHASE_ODD(buf, ks, sb, sk, skt)                                       \
  {                                                                           \
    b[2] = *(const bf16x8*)&LB[buf][ks][boff + 1024];                         \
    b[3] = *(const bf16x8*)&LB[buf][ks][boff + 1536];                         \
    STAGE(sb, sk, skt, 1);                                                    \
    asm volatile("s_barrier" ::: "memory");                                   \
    __builtin_amdgcn_s_setprio(1);                                            \
    _Pragma("unroll") for (int m_ = 0; m_ < 8; ++m_) {                        \
      acc[m_][2] = MFMA_(a[m_], b[2], acc[m_][2], 0, 0, 0);                   \
      acc[m_][3] = MFMA_(a[m_], b[3], acc[m_][3], 0, 0, 0);                   \
    }                                                                         \
    __builtin_amdgcn_s_setprio(0);                                            \
    asm volatile("s_waitcnt vmcnt(8)");                                       \
    asm volatile("s_barrier" ::: "memory");                                   \
  }

  const int NT = K >> 6;

  STAGE(0, 0, 0, 0); STAGE(0, 0, 0, 1);
  STAGE(0, 1, 0, 0); STAGE(0, 1, 0, 1);
  STAGE(1, 0, 1, 0); STAGE(1, 0, 1, 1);
  asm volatile("s_waitcnt vmcnt(8)");
  asm volatile("s_barrier" ::: "memory");

  for (int i = 0; i < (NT >> 1); ++i) {
    const int kt0 = 2 * i;
    const int ktA = (kt0 + 2 < NT) ? kt0 + 2 : NT - 1;
    const int ktB = (kt0 + 3 < NT) ? kt0 + 3 : NT - 1;
    PHASE_EVEN(0, 0, 1, 1, kt0 + 1)
    PHASE_ODD (0, 0, 1, 1, kt0 + 1)
    PHASE_EVEN(0, 1, 0, 0, ktA)
    PHASE_ODD (0, 1, 0, 0, ktA)
    PHASE_EVEN(1, 0, 0, 1, ktA)
    PHASE_ODD (1, 0, 0, 1, ktA)
    PHASE_EVEN(1, 1, 1, 0, ktB)
    PHASE_ODD (1, 1, 1, 0, ktB)
  }
#undef PHASE_EVEN
#undef PHASE_ODD
#undef STAGE

  const int crow0 = m0 + wr * 128 + l4 * 4;
  const int ccol0 = n0 + wc * 64 + l15;
#pragma unroll
  for (int m_ = 0; m_ < 8; ++m_)
#pragma unroll
    for (int n_ = 0; n_ < 4; ++n_)
#pragma unroll
      for (int r_ = 0; r_ < 4; ++r_) {
        const size_t row = crow0 + m_ * 16 + r_;
        const int col = ccol0 + n_ * 16;
        const float val = acc[m_][n_][r_];
        if (OUT_BF16) ((ushort*)Cp)[row * N + col] = f2bf(val);
        else          ((float*)Cp)[row * N + col]  = val;
      }
}

// ---------------------------------------------------------------------------
// RoPE in place on bf16 buffer: element (b,s,h,j) at buf[(b*S+s)*ld + h*HD + j]
// ---------------------------------------------------------------------------
__global__ __launch_bounds__(256)
void rope_kernel(ushort* buf, const int* __restrict__ pos_ids, int nh, int ld, int total) {
  int t = blockIdx.x * 256 + threadIdx.x;
  if (t >= total) return;
  int j = t & 63;
  int rest = t >> 6;
  int h = rest % nh;
  int bs = rest / nh;
  float pos = (float)pos_ids[bs];
  float inv = exp2f(-(float)j * (13.287712379549449f / 64.0f));
  float ang = pos * inv;
  float c = cosf(ang), s = sinf(ang);
  ushort* p = buf + (size_t)bs * ld + h * HD + j;
  float x1 = bf2f(p[0]), x2 = bf2f(p[64]);
  p[0]  = f2bf(x1 * c - x2 * s);
  p[64] = f2bf(x2 * c + x1 * s);
}

// ---------------------------------------------------------------------------
// Flash attention, causal, GQA-shared K/V.
// Block = (32 q-rows) x (one KV group = 4 heads); wave w handles head kh*4+w.
// K staged from QKV (roped); V staged from pre-transposed VtG — both via
// global_load_lds with pre-swizzled source (zero staging VALU).
// Defer-max with per-lane threshold check (no shuffle tree in common path).
// ---------------------------------------------------------------------------
__global__ __launch_bounds__(256)
void attn_kernel(const ushort* __restrict__ Q, const ushort* __restrict__ K0,
                 const ushort* __restrict__ VtG, ushort* __restrict__ AO) {
  __shared__ ushort Ks[64 * 128];       // [k][d], slot^=(k&7), 16KB
  __shared__ ushort Vs[2][128 * 64];    // [d][k], slot^=(d&7), 2x16KB
  __shared__ ushort Ps[4][32 * 72];     // per-wave P tile 32x64, pad 72

  const int raw  = blockIdx.x;
  const int kh   = raw & 7;             // kv-head -> XCD (L2-resident K/V)
  const int rest = raw >> 3;
  const int qt   = 63 - (rest & 63);    // longest blocks first (LPT)
  const int b    = rest >> 6;
  const int q0   = qt * 32;

  const int tid = threadIdx.x, lane = tid & 63, wave = tid >> 6;
  const int l15 = lane & 15, l4 = lane >> 4;
  const int h = kh * 4 + wave;
  const float SCL2 = 0.1275173110f;     // (1/sqrt(128)) * log2(e)

  const size_t bS = (size_t)b * SEQ;
  const ushort* Kb = K0 + bS * QKVLD + kh * HD;
  const ushort* Vb = VtG + (size_t)(b * NKV + kh) * HD * SEQ;

  const int vrow = lane >> 3;           // V stage: within-chunk d row 0..7
  const int vslot = lane & 7;           // V stage: 16B slot

  // ---- Q fragments: 32 rows x 128 d per wave ----
  bf16x8 qf[2][4];
#pragma unroll
  for (int mi = 0; mi < 2; ++mi) {
    const ushort* qp = Q + (bS + q0 + mi * 16 + l15) * QKVLD + h * HD + l4 * 8;
#pragma unroll
    for (int kk = 0; kk < 4; ++kk) qf[mi][kk] = *(const bf16x8*)(qp + kk * 32);
  }

  float mrow[2][4], denom[2][4];
#pragma unroll
  for (int mi = 0; mi < 2; ++mi)
#pragma unroll
    for (int r = 0; r < 4; ++r) { mrow[mi][r] = -1e30f; denom[mi][r] = 0.0f; }
  f32x4 accO[2][8] = {};

  const int nt = qt / 2 + 1;  // causal coverage

  // ---- prologue: stage K(0) and V(0), both via global_load_lds ----
  {
#pragma unroll
    for (int c = 0; c < 4; ++c) {
      const int j = wave * 4 + c;
      const int row = j * 4 + l4;
      const int chunk = l15 ^ (row & 7);
      gload_lds16(Kb + (size_t)row * QKVLD + chunk * 8, &Ks[j * 512 + lane * 8]);
    }
#pragma unroll
    for (int c = 0; c < 4; ++c) {
      const int j = wave * 4 + c;
      const int d = j * 8 + vrow;
      const int chunk = vslot ^ (d & 7);
      gload_lds16(Vb + (size_t)d * SEQ + chunk * 8, &Vs[0][j * 512 + lane * 8]);
    }
  }
  __syncthreads();

  for (int t = 0; t < nt; ++t) {
    const int k0 = t * 64;
    const int cur = t & 1;
    const bool mask_tile = (t == nt - 1);
    const bool pf = (t + 1 < nt);

    // ---- QK^T ----
    f32x4 accS[2][4] = {};
    __builtin_amdgcn_s_setprio(1);
#pragma unroll
    for (int kk = 0; kk < 4; ++kk) {
#pragma unroll
      for (int ni = 0; ni < 4; ++ni) {
        bf16x8 kf = *(const bf16x8*)&Ks[(ni * 16 + l15) * 128 +
                                        (((kk * 4 + l4) ^ (l15 & 7)) << 3)];
        accS[0][ni] = __builtin_amdgcn_mfma_f32_16x16x32_bf16(qf[0][kk], kf, accS[0][ni], 0, 0, 0);
        accS[1][ni] = __builtin_amdgcn_mfma_f32_16x16x32_bf16(qf[1][kk], kf, accS[1][ni], 0, 0, 0);
      }
    }
    __builtin_amdgcn_s_setprio(0);
    __syncthreads();   // all waves done reading Ks / prior Vs

    // ---- issue next tile's K+V loads (hide under softmax+PV) ----
    if (pf) {
      const int kn = k0 + 64;
#pragma unroll
      for (int c = 0; c < 4; ++c) {
        const int j = wave * 4 + c;
        const int row = j * 4 + l4;
        const int chunk = l15 ^ (row & 7);
        gload_lds16(Kb + (size_t)(kn + row) * QKVLD + chunk * 8, &Ks[j * 512 + lane * 8]);
      }
#pragma unroll
      for (int c = 0; c < 4; ++c) {
        const int j = wave * 4 + c;
        const int d = j * 8 + vrow;
        const int chunk = vslot ^ (d & 7);
        gload_lds16(Vb + (size_t)d * SEQ + kn + chunk * 8,
                    &Vs[cur ^ 1][j * 512 + lane * 8]);
      }
    }

    // ---- softmax (defer-max, PER-LANE threshold check) ----
    float pmax[2][4];
#pragma unroll
    for (int mi = 0; mi < 2; ++mi)
#pragma unroll
      for (int r = 0; r < 4; ++r) {
        float mx = -3e38f;
#pragma unroll
        for (int ni = 0; ni < 4; ++ni) {
          float x = accS[mi][ni][r] * SCL2;
          if (mask_tile) {
            int kq = k0 + ni * 16 + l15;
            int qq = q0 + mi * 16 + l4 * 4 + r;
            if (kq > qq) x = -1e30f;
          }
          accS[mi][ni][r] = x;
          mx = fmaxf(mx, x);
        }
        pmax[mi][r] = mx;   // per-lane max (not yet row-reduced)
      }

    bool ok = true;
#pragma unroll
    for (int mi = 0; mi < 2; ++mi)
#pragma unroll
      for (int r = 0; r < 4; ++r)
        ok = ok && (pmax[mi][r] - mrow[mi][r] <= 8.0f);

    if (__all(ok)) {
      // deferred: row max unchanged, per-lane check implies row check
#pragma unroll
      for (int mi = 0; mi < 2; ++mi)
#pragma unroll
        for (int r = 0; r < 4; ++r) {
          const float mn = mrow[mi][r];
          float s = 0.0f;
#pragma unroll
          for (int ni = 0; ni < 4; ++ni) {
            float p = exp2f(accS[mi][ni][r] - mn);
            accS[mi][ni][r] = p;
            s += p;
          }
          denom[mi][r] += s;
        }
    } else {
      // full row reduce, then rescale
#pragma unroll
      for (int d = 1; d < 16; d <<= 1)
#pragma unroll
        for (int mi = 0; mi < 2; ++mi)
#pragma unroll
          for (int r = 0; r < 4; ++r)
            pmax[mi][r] = fmaxf(pmax[mi][r], __shfl_xor(pmax[mi][r], d));
#pragma unroll
      for (int mi = 0; mi < 2; ++mi)
#pragma unroll
        for (int r = 0; r < 4; ++r) {
          const float mn = fmaxf(mrow[mi][r], pmax[mi][r]);
          const float alpha = exp2f(mrow[mi][r] - mn);
          mrow[mi][r] = mn;
          float s = 0.0f;
#pragma unroll
          for (int ni = 0; ni < 4; ++ni) {
            float p = exp2f(accS[mi][ni][r] - mn);
            accS[mi][ni][r] = p;
            s += p;
          }
          denom[mi][r] = denom[mi][r] * alpha + s;
#pragma unroll
          for (int db = 0; db < 8; ++db) accO[mi][db][r] *= alpha;
        }
    }

    // ---- write P to per-wave LDS tile ----
#pragma unroll
    for (int mi = 0; mi < 2; ++mi)
#pragma unroll
      for (int ni = 0; ni < 4; ++ni)
#pragma unroll
        for (int r = 0; r < 4; ++r)
          Ps[wave][(mi * 16 + l4 * 4 + r) * 72 + ni * 16 + l15] = f2bf(accS[mi][ni][r]);

    // ---- PV ----
    __builtin_amdgcn_s_setprio(1);
#pragma unroll
    for (int kk = 0; kk < 2; ++kk) {
      bf16x8 pa[2];
#pragma unroll
      for (int mi = 0; mi < 2; ++mi)
        pa[mi] = *(const bf16x8*)&Ps[wave][(mi * 16 + l15) * 72 + kk * 32 + l4 * 8];
#pragma unroll
      for (int db = 0; db < 8; ++db) {
        bf16x8 vb = *(const bf16x8*)&Vs[cur][(db * 16 + l15) * 64 +
                                            (((kk * 4 + l4) ^ (l15 & 7)) << 3)];
        accO[0][db] = __builtin_amdgcn_mfma_f32_16x16x32_bf16(pa[0], vb, accO[0][db], 0, 0, 0);
        accO[1][db] = __builtin_amdgcn_mfma_f32_16x16x32_bf16(pa[1], vb, accO[1][db], 0, 0, 0);
      }
    }
    __builtin_amdgcn_s_setprio(0);

    __syncthreads();   // drains K(t+1)/V(t+1) gloads; ends Vs[cur]/Ps reads
  }

  // ---- epilogue: reduce denom across l15, divide, store ----
#pragma unroll
  for (int d = 1; d < 16; d <<= 1)
#pragma unroll
    for (int mi = 0; mi < 2; ++mi)
#pragma unroll
      for (int r = 0; r < 4; ++r)
        denom[mi][r] += __shfl_xor(denom[mi][r], d);

#pragma unroll
  for (int mi = 0; mi < 2; ++mi)
#pragma unroll
    for (int db = 0; db < 8; ++db)
#pragma unroll
      for (int r = 0; r < 4; ++r) {
        int q = q0 + mi * 16 + l4 * 4 + r;
        int col = h * HD + db * 16 + l15;
        AO[(bS + q) * HIDDEN + col] = f2bf(accO[mi][db][r] / denom[mi][r]);
      }
}

// ---------------------------------------------------------------------------
extern "C" void kernel_launch(void* const* d_in, const int* in_sizes, int n_in,
                              void* d_out, int out_size, void* d_ws, size_t ws_size,
                              hipStream_t stream) {
  (void)in_sizes; (void)n_in; (void)out_size; (void)ws_size;
  const float* X   = (const float*)d_in[0];
  const int*   pos = (const int*)d_in[2];
  const float* Wq  = (const float*)d_in[3];
  const float* Wk  = (const float*)d_in[4];
  const float* Wv  = (const float*)d_in[5];
  const float* Wo  = (const float*)d_in[6];

  char* ws = (char*)d_ws;
  ushort* Xb    = (ushort*)(ws);                    // 33,554,432 B (aliased by AO)
  ushort* QKV   = (ushort*)(ws + 33554432);         // 50,331,648 B  [M][6144]
  ushort* BTqkv = (ushort*)(ws + 83886080);         // 50,331,648 B
  ushort* WoT   = (ushort*)(ws + 134217728);        // 33,554,432 B
  ushort* AO    = Xb;                               // X dead after QKV projection
  ushort* VtG   = BTqkv;                            // BTqkv dead after QKV GEMM (8MB used)

  const int M = BSZ * SEQ;  // 4096
  dim3 blk(256);

  hipFuncSetAttribute((const void*)gemm8p_kernel<1>,
                      hipFuncAttributeMaxDynamicSharedMemorySize, 131072);
  hipFuncSetAttribute((const void*)gemm8p_kernel<0>,
                      hipFuncAttributeMaxDynamicSharedMemorySize, 131072);

  // ---- pre-passes ----
  cvt_bf16_kernel<<<dim3((M * HIDDEN / 8 + 255) / 256), blk, 0, stream>>>(X, Xb, M * HIDDEN / 8);
  transpose_bf16_kernel<<<dim3(HIDDEN / 32, HIDDEN / 32), blk, 0, stream>>>(Wq, BTqkv, HIDDEN, HIDDEN);
  transpose_bf16_kernel<<<dim3((NKV * HD) / 32, HIDDEN / 32), blk, 0, stream>>>(
      Wk, BTqkv + (size_t)HIDDEN * HIDDEN, HIDDEN, NKV * HD);
  transpose_bf16_kernel<<<dim3((NKV * HD) / 32, HIDDEN / 32), blk, 0, stream>>>(
      Wv, BTqkv + (size_t)(HIDDEN + NKV * HD) * HIDDEN, HIDDEN, NKV * HD);
  transpose_bf16_kernel<<<dim3(HIDDEN / 32, HIDDEN / 32), blk, 0, stream>>>(Wo, WoT, HIDDEN, HIDDEN);

  // ---- fused QKV projection ----
  gemm8p_kernel<1><<<dim3((M / 256) * (QKVN / 256)), dim3(512), 131072, stream>>>(
      Xb, BTqkv, QKV, M, QKVN, HIDDEN);

  // ---- RoPE in place (Q, K) + V transpose (VtG aliases dead BTqkv) ----
  rope_kernel<<<dim3((M * NH * 64) / 256), blk, 0, stream>>>(QKV, pos, NH, QKVLD, M * NH * 64);
  rope_kernel<<<dim3((M * NKV * 64) / 256), blk, 0, stream>>>(QKV + HIDDEN, pos, NKV, QKVLD, M * NKV * 64);
  transpose_v_kernel<<<dim3(SEQ / 32, HD / 32, BSZ * NKV), blk, 0, stream>>>(
      QKV + HIDDEN + NKV * HD, VtG);

  // ---- flash attention ----
  attn_kernel<<<dim3(8 * 64 * BSZ), blk, 0, stream>>>(QKV, QKV + HIDDEN, VtG, AO);

  // ---- output projection -> fp32 d_out ----
  gemm8p_kernel<0><<<dim3((M / 256) * (HIDDEN / 256)), dim3(512), 131072, stream>>>(
      AO, WoT, d_out, M, HIDDEN, HIDDEN);
}

// Round 8
// 598.025 us; speedup vs baseline: 1.4275x; 1.0686x over previous
//
#include <hip/hip_runtime.h>
#include <hip/hip_bf16.h>
#include <cstdint>

#define HIDDEN 4096
#define NH 32
#define NKV 8
#define HD 128
#define SEQ 2048
#define BSZ 2
#define QKVN 6144          // fused QKV projection width
#define QKVLD 6144         // row stride of fused QKV buffer

using bf16x8 = __attribute__((ext_vector_type(8))) short;
using f32x4  = __attribute__((ext_vector_type(4))) float;
using f32x16 = __attribute__((ext_vector_type(16))) float;

__device__ __forceinline__ ushort f2bf(float f) {
  union { float f; uint32_t u; } v; v.f = f;
  uint32_t r = (v.u + 0x7FFFu + ((v.u >> 16) & 1u)) >> 16;  // RNE
  return (ushort)r;
}
__device__ __forceinline__ float bf2f(ushort s) {
  union { uint32_t u; float f; } v; v.u = ((uint32_t)s) << 16;
  return v.f;
}

__device__ __forceinline__ uint32_t cvtpk(float lo, float hi) {
  uint32_t r;
  asm("v_cvt_pk_bf16_f32 %0, %1, %2" : "=v"(r) : "v"(lo), "v"(hi));
  return r;
}
__device__ __forceinline__ void pl32swap(uint32_t& a, uint32_t& b) {
  // vdst lanes32-63 <-> vsrc lanes0-31
  asm("v_permlane32_swap_b32 %0, %1" : "+v"(a), "+v"(b));
}

__device__ __forceinline__ void gload_lds16(const void* g, void* l) {
  __builtin_amdgcn_global_load_lds(
      (const __attribute__((address_space(1))) void*)g,
      (__attribute__((address_space(3))) void*)l, 16, 0, 0);
}

// ---------------------------------------------------------------------------
// fp32 -> bf16 elementwise convert (vectorized, 8 elems/thread)
// ---------------------------------------------------------------------------
__global__ __launch_bounds__(256)
void cvt_bf16_kernel(const float* __restrict__ X, ushort* __restrict__ Xb, int n8) {
  int t = blockIdx.x * 256 + threadIdx.x;
  if (t >= n8) return;
  size_t i = (size_t)t * 8;
  float4 a = *(const float4*)(X + i);
  float4 b = *(const float4*)(X + i + 4);
  uint4 p;
  p.x = (uint)f2bf(a.x) | ((uint)f2bf(a.y) << 16);
  p.y = (uint)f2bf(a.z) | ((uint)f2bf(a.w) << 16);
  p.z = (uint)f2bf(b.x) | ((uint)f2bf(b.y) << 16);
  p.w = (uint)f2bf(b.z) | ((uint)f2bf(b.w) << 16);
  *(uint4*)(Xb + i) = p;
}

// ---------------------------------------------------------------------------
// W[K][N] fp32 -> WT[N][K] bf16 (32x32 LDS tile transpose)
// ---------------------------------------------------------------------------
__global__ __launch_bounds__(256)
void transpose_bf16_kernel(const float* __restrict__ W, ushort* __restrict__ WT,
                           int K, int N) {
  __shared__ ushort tile[32][33];
  const int k0 = blockIdx.y * 32, n0 = blockIdx.x * 32;
  const int tx = threadIdx.x & 31, ty = threadIdx.x >> 5;  // ty 0..7
  for (int i = 0; i < 4; ++i) {
    int k = ty + i * 8;
    tile[k][tx] = f2bf(W[(size_t)(k0 + k) * N + n0 + tx]);
  }
  __syncthreads();
  for (int i = 0; i < 4; ++i) {
    int n = ty + i * 8;
    WT[(size_t)(n0 + n) * K + k0 + tx] = tile[tx][n];
  }
}

// ---------------------------------------------------------------------------
// V part of QKV -> per-head transposed VtG[(b*NKV+kh)][d=128][SEQ] (bf16)
// ---------------------------------------------------------------------------
__global__ __launch_bounds__(256)
void transpose_v_kernel(const ushort* __restrict__ Vsrc, ushort* __restrict__ VtG) {
  __shared__ ushort tile[32][33];
  const int slice = blockIdx.z;                 // b*NKV + kh
  const int b = slice >> 3, kh = slice & 7;
  const int s0 = blockIdx.x * 32, d0 = blockIdx.y * 32;
  const int tx = threadIdx.x & 31, ty = threadIdx.x >> 5;  // ty 0..7
  const ushort* src = Vsrc + ((size_t)(b * SEQ) + s0) * QKVLD + kh * HD + d0;
  for (int i = 0; i < 4; ++i) {
    int s = ty + i * 8;
    tile[s][tx] = src[(size_t)s * QKVLD + tx];
  }
  __syncthreads();
  ushort* dst = VtG + ((size_t)slice * HD + d0) * SEQ + s0;
  for (int i = 0; i < 4; ++i) {
    int d = ty + i * 8;
    dst[(size_t)d * SEQ + tx] = tile[tx][d];
  }
}

// ---------------------------------------------------------------------------
// 256x256 8-phase GEMM: C[MxN] = A[MxK] * BT[NxK]^T, bf16 inputs.
// ---------------------------------------------------------------------------
template<int OUT_BF16>
__global__ __launch_bounds__(512, 2)
void gemm8p_kernel(const ushort* __restrict__ A, const ushort* __restrict__ BT,
                   void* __restrict__ Cp, int M, int N, int K) {
  extern __shared__ ushort lds[];   // 128 KB
  const int tid = threadIdx.x, lane = tid & 63, wave = tid >> 6;
  const int l15 = lane & 15, l4 = lane >> 4;
  const int wr = wave >> 2, wc = wave & 3;

  const int mt = M >> 8, nt = N >> 8, nwg = mt * nt;
  const int swq = nwg >> 3, swr = nwg & 7;
  const int xcd = blockIdx.x & 7, lo = blockIdx.x >> 3;
  const int wg = (xcd < swr ? xcd * (swq + 1) : swr * (swq + 1) + (xcd - swr) * swq) + lo;
  const int m0 = (wg % mt) << 8;
  const int n0 = (wg / mt) << 8;

  ushort* LA[2][2];
  ushort* LB[2][2];
#pragma unroll
  for (int b_ = 0; b_ < 2; ++b_)
#pragma unroll
    for (int s_ = 0; s_ < 2; ++s_) {
      LA[b_][s_] = lds + ((b_ * 2 + 0) * 2 + s_) * 8192;
      LB[b_][s_] = lds + ((b_ * 2 + 1) * 2 + s_) * 8192;
    }

  const ushort* Abase = A + (size_t)m0 * K;
  const ushort* Bbase = BT + (size_t)n0 * K;

  const int srow0 = tid >> 2;
  const int scol8 = (((tid & 3) ^ ((srow0 >> 1) & 3)) << 3);

  const int swb  = (l4 ^ ((l15 >> 1) & 3)) << 3;
  const int aoff = (wr * 128 + l15) * 32 + swb;
  const int boff = (wc * 64 + l15) * 32 + swb;

  f32x4 acc[8][4] = {};
  bf16x8 a[8];
  bf16x8 b[4];

#define STAGE(buf, ks, kt, part)                                              \
  do {                                                                        \
    const size_t gc_ = (size_t)(kt) * 64 + (ks) * 32 + scol8;                 \
    const int rw_ = srow0 + (part) * 128;                                     \
    const int dst_ = ((part) * 512 + tid) * 8;                                \
    gload_lds16(Abase + (size_t)rw_ * K + gc_, &LA[buf][ks][dst_]);           \
    gload_lds16(Bbase + (size_t)rw_ * K + gc_, &LB[buf][ks][dst_]);           \
  } while (0)

#define MFMA_ __builtin_amdgcn_mfma_f32_16x16x32_bf16

#define PHASE_EVEN(buf, ks, sb, sk, skt)                                      \
  {                                                                           \
    _Pragma("unroll") for (int m_ = 0; m_ < 8; ++m_)                          \
      a[m_] = *(const bf16x8*)&LA[buf][ks][aoff + m_ * 512];                  \
    b[0] = *(const bf16x8*)&LB[buf][ks][boff];                                \
    b[1] = *(const bf16x8*)&LB[buf][ks][boff + 512];                          \
    STAGE(sb, sk, skt, 0);                                                    \
    asm volatile("s_barrier" ::: "memory");                                   \
    __builtin_amdgcn_s_setprio(1);                                            \
    _Pragma("unroll") for (int m_ = 0; m_ < 8; ++m_) {                        \
      acc[m_][0] = MFMA_(a[m_], b[0], acc[m_][0], 0, 0, 0);                   \
      acc[m_][1] = MFMA_(a[m_], b[1], acc[m_][1], 0, 0, 0);                   \
    }                                                                         \
    __builtin_amdgcn_s_setprio(0);                                            \
    asm volatile("s_barrier" ::: "memory");                                   \
  }

#define PHASE_ODD(buf, ks, sb, sk, skt)                                       \
  {                                                                           \
    b[2] = *(const bf16x8*)&LB[buf][ks][boff + 1024];                         \
    b[3] = *(const bf16x8*)&LB[buf][ks][boff + 1536];                         \
    STAGE(sb, sk, skt, 1);                                                    \
    asm volatile("s_barrier" ::: "memory");                                   \
    __builtin_amdgcn_s_setprio(1);                                            \
    _Pragma("unroll") for (int m_ = 0; m_ < 8; ++m_) {                        \
      acc[m_][2] = MFMA_(a[m_], b[2], acc[m_][2], 0, 0, 0);                   \
      acc[m_][3] = MFMA_(a[m_], b[3], acc[m_][3], 0, 0, 0);                   \
    }                                                                         \
    __builtin_amdgcn_s_setprio(0);                                            \
    asm volatile("s_waitcnt vmcnt(8)");                                       \
    asm volatile("s_barrier" ::: "memory");                                   \
  }

  const int NT = K >> 6;

  STAGE(0, 0, 0, 0); STAGE(0, 0, 0, 1);
  STAGE(0, 1, 0, 0); STAGE(0, 1, 0, 1);
  STAGE(1, 0, 1, 0); STAGE(1, 0, 1, 1);
  asm volatile("s_waitcnt vmcnt(8)");
  asm volatile("s_barrier" ::: "memory");

  for (int i = 0; i < (NT >> 1); ++i) {
    const int kt0 = 2 * i;
    const int ktA = (kt0 + 2 < NT) ? kt0 + 2 : NT - 1;
    const int ktB = (kt0 + 3 < NT) ? kt0 + 3 : NT - 1;
    PHASE_EVEN(0, 0, 1, 1, kt0 + 1)
    PHASE_ODD (0, 0, 1, 1, kt0 + 1)
    PHASE_EVEN(0, 1, 0, 0, ktA)
    PHASE_ODD (0, 1, 0, 0, ktA)
    PHASE_EVEN(1, 0, 0, 1, ktA)
    PHASE_ODD (1, 0, 0, 1, ktA)
    PHASE_EVEN(1, 1, 1, 0, ktB)
    PHASE_ODD (1, 1, 1, 0, ktB)
  }
#undef PHASE_EVEN
#undef PHASE_ODD
#undef STAGE

  const int crow0 = m0 + wr * 128 + l4 * 4;
  const int ccol0 = n0 + wc * 64 + l15;
#pragma unroll
  for (int m_ = 0; m_ < 8; ++m_)
#pragma unroll
    for (int n_ = 0; n_ < 4; ++n_)
#pragma unroll
      for (int r_ = 0; r_ < 4; ++r_) {
        const size_t row = crow0 + m_ * 16 + r_;
        const int col = ccol0 + n_ * 16;
        const float val = acc[m_][n_][r_];
        if (OUT_BF16) ((ushort*)Cp)[row * N + col] = f2bf(val);
        else          ((float*)Cp)[row * N + col]  = val;
      }
}

// ---------------------------------------------------------------------------
// RoPE in place (optionally folding an output scale into cos/sin).
// ---------------------------------------------------------------------------
__global__ __launch_bounds__(256)
void rope_kernel(ushort* buf, const int* __restrict__ pos_ids, int nh, int ld,
                 int total, float oscale) {
  int t = blockIdx.x * 256 + threadIdx.x;
  if (t >= total) return;
  int j = t & 63;
  int rest = t >> 6;
  int h = rest % nh;
  int bs = rest / nh;
  float pos = (float)pos_ids[bs];
  float inv = exp2f(-(float)j * (13.287712379549449f / 64.0f));
  float ang = pos * inv;
  float c = cosf(ang) * oscale, s = sinf(ang) * oscale;
  ushort* p = buf + (size_t)bs * ld + h * HD + j;
  float x1 = bf2f(p[0]), x2 = bf2f(p[64]);
  p[0]  = f2bf(x1 * c - x2 * s);
  p[64] = f2bf(x2 * c + x1 * s);
}

// ---------------------------------------------------------------------------
// Flash attention, causal, GQA. 8 warps x 32 q-rows (block = 256 q x 1 head).
// Swapped QK^T (32x32x16 MFMA): S^T = mfma(K,Q) -> lane holds full P-row for
// q = lane&31 in registers. P -> PV B-frags via cvt_pk + permlane32_swap
// (no LDS for P). PV: O^T = mfma(V^T, P^T) keeps q in C-cols -> scalar
// mrow/denom per lane. K single-buffered LDS (16-slot XOR swizzle), V^T
// double-buffered (8-slot swizzle), both staged via global_load_lds.
// Q pre-scaled by 1/sqrt(128)*log2(e) during RoPE (softmax in exp2 domain).
// ---------------------------------------------------------------------------
__global__ __launch_bounds__(512)
void attn_kernel(const ushort* __restrict__ Q, const ushort* __restrict__ K0,
                 const ushort* __restrict__ VtG, ushort* __restrict__ AO) {
  __shared__ ushort Ks[64 * 128];       // [k][d], slot16 ^= (k&15), 16KB
  __shared__ ushort Vs[2][128 * 64];    // [d][k], slot8 ^= (d&7), 2x16KB

  const int bid = blockIdx.x;
  const int kh  = bid & 7;              // kv-head -> XCD (L2-resident K/V)
  const int r2  = bid >> 3;
  const int qtB = 7 - (r2 & 7);         // LPT: longest q-tiles first
  const int hq  = (r2 >> 3) & 3;
  const int b   = r2 >> 5;
  const int h   = kh * 4 + hq;
  const int q0b = qtB * 256;

  const int tid = threadIdx.x, lane = tid & 63, w = tid >> 6;
  const int l31 = lane & 31, hi = lane >> 5;
  const int q0w = q0b + w * 32;

  const size_t bS = (size_t)b * SEQ;
  const ushort* Kb = K0 + bS * QKVLD + kh * HD;
  const ushort* Vb = VtG + (size_t)(b * NKV + kh) * HD * SEQ;

  // ---- Q fragments: B-operand, lane holds Q[q=l31][d = ds*16 + hi*8 + j] ----
  bf16x8 qf[8];
  {
    const ushort* qp = Q + (bS + q0w + l31) * QKVLD + h * HD + hi * 8;
#pragma unroll
    for (int ds = 0; ds < 8; ++ds) qf[ds] = *(const bf16x8*)(qp + ds * 16);
  }

  f32x16 accO[4] = {};                  // O^T: col q=l31, rows d (4 x 32-d subtiles)
  float mrow = -1e30f, denom = 0.0f;

  const int nt = qtB * 4 + 4;

  const int j0 = 2 * w, j1 = 2 * w + 1; // this warp's staging chunks
  const int kl4 = lane >> 4, ks15 = lane & 15;
  const int vl3 = lane >> 3, vs7 = lane & 7;
  const int kswz = lane & 15;           // = (k&15) at read (k = ksub*32 + l31)
  const int vswz = lane & 7;            // = (d&7) at read

#define KSTAGE(jj, kk0) { const int k_ = (jj) * 4 + kl4;                       \
    gload_lds16(Kb + (size_t)((kk0) + k_) * QKVLD + ((ks15 ^ (k_ & 15)) << 3), \
                &Ks[(jj) * 512 + lane * 8]); }
#define VSTAGE(jj, bb, kk0) { const int d_ = (jj) * 8 + vl3;                   \
    gload_lds16(Vb + (size_t)d_ * SEQ + (kk0) + ((vs7 ^ (d_ & 7)) << 3),       \
                &Vs[bb][(jj) * 512 + lane * 8]); }

  // ---- prologue: stage K(0), V(0) ----
  KSTAGE(j0, 0) KSTAGE(j1, 0) VSTAGE(j0, 0, 0) VSTAGE(j1, 0, 0)
  __syncthreads();

  for (int t = 0; t < nt; ++t) {
    const int k0 = t * 64;
    const int cur = t & 1;
    const bool pf = (t + 1 < nt);
    const bool skip = (k0 > q0w + 31);   // warp-uniform: tile fully masked

    // ---- QK^T: S^T[k][q], accumulate over 8 d-slices ----
    f32x16 s0 = {}, s1 = {};
    if (!skip) {
      __builtin_amdgcn_s_setprio(1);
#pragma unroll
      for (int ds = 0; ds < 8; ++ds) {
        const int so = ((ds * 2 + hi) ^ kswz) << 3;
        bf16x8 kf0 = *(const bf16x8*)&Ks[l31 * 128 + so];
        bf16x8 kf1 = *(const bf16x8*)&Ks[(32 + l31) * 128 + so];
        s0 = __builtin_amdgcn_mfma_f32_32x32x16_bf16(kf0, qf[ds], s0, 0, 0, 0);
        s1 = __builtin_amdgcn_mfma_f32_32x32x16_bf16(kf1, qf[ds], s1, 0, 0, 0);
      }
      __builtin_amdgcn_s_setprio(0);
    }
    __syncthreads();                     // all warps done reading Ks / old Vs

    // ---- issue next tile's staging (latency hides under softmax+PV) ----
    if (pf) {
      const int kn = k0 + 64;
      KSTAGE(j0, kn) KSTAGE(j1, kn) VSTAGE(j0, cur ^ 1, kn) VSTAGE(j1, cur ^ 1, kn)
    }

    if (!skip) {
      // ---- causal mask (only near-diagonal tiles) ----
      if (k0 + 63 > q0w) {
        const int qrel = q0w + l31 - k0;
#pragma unroll
        for (int r = 0; r < 16; ++r) {
          const int kc = (r & 3) + 8 * (r >> 2) + 4 * hi;
          if (kc > qrel)      s0[r] = -1e30f;
          if (kc + 32 > qrel) s1[r] = -1e30f;
        }
      }
      // ---- per-lane max (full row is in-lane + hi-partner) ----
      float pm = s0[0];
#pragma unroll
      for (int r = 1; r < 16; ++r) pm = fmaxf(pm, s0[r]);
#pragma unroll
      for (int r = 0; r < 16; ++r) pm = fmaxf(pm, s1[r]);

      if (!__all(pm - mrow <= 8.0f)) {
        pm = fmaxf(pm, __shfl_xor(pm, 32));
        const float mn = fmaxf(mrow, pm);
        const float alpha = exp2f(mrow - mn);
        mrow = mn;
        denom *= alpha;
#pragma unroll
        for (int du = 0; du < 4; ++du)
#pragma unroll
          for (int r = 0; r < 16; ++r) accO[du][r] *= alpha;
      }
      // ---- P = exp2(S - mrow), per-lane partial denom ----
      float ssum = 0.0f;
#pragma unroll
      for (int r = 0; r < 16; ++r) { float p = exp2f(s0[r] - mrow); s0[r] = p; ssum += p; }
#pragma unroll
      for (int r = 0; r < 16; ++r) { float p = exp2f(s1[r] - mrow); s1[r] = p; ssum += p; }
      denom += ssum;

      // ---- pack P to bf16 + permlane -> 4 PV B-frags (k-slices of 16) ----
      uint32_t paw[4][4];
      {
        uint32_t p0 = cvtpk(s0[0], s0[1]),   p1 = cvtpk(s0[2], s0[3]);
        uint32_t p2 = cvtpk(s0[4], s0[5]),   p3 = cvtpk(s0[6], s0[7]);
        uint32_t p4 = cvtpk(s0[8], s0[9]),   p5 = cvtpk(s0[10], s0[11]);
        uint32_t p6 = cvtpk(s0[12], s0[13]), p7 = cvtpk(s0[14], s0[15]);
        pl32swap(p0, p2); pl32swap(p1, p3); pl32swap(p4, p6); pl32swap(p5, p7);
        paw[0][0] = p0; paw[0][1] = p1; paw[0][2] = p2; paw[0][3] = p3;
        paw[1][0] = p4; paw[1][1] = p5; paw[1][2] = p6; paw[1][3] = p7;
      }
      {
        uint32_t p0 = cvtpk(s1[0], s1[1]),   p1 = cvtpk(s1[2], s1[3]);
        uint32_t p2 = cvtpk(s1[4], s1[5]),   p3 = cvtpk(s1[6], s1[7]);
        uint32_t p4 = cvtpk(s1[8], s1[9]),   p5 = cvtpk(s1[10], s1[11]);
        uint32_t p6 = cvtpk(s1[12], s1[13]), p7 = cvtpk(s1[14], s1[15]);
        pl32swap(p0, p2); pl32swap(p1, p3); pl32swap(p4, p6); pl32swap(p5, p7);
        paw[2][0] = p0; paw[2][1] = p1; paw[2][2] = p2; paw[2][3] = p3;
        paw[3][0] = p4; paw[3][1] = p5; paw[3][2] = p6; paw[3][3] = p7;
      }

      // ---- PV: O^T[d][q] += V^T-frag x P-frag ----
      __builtin_amdgcn_s_setprio(1);
#pragma unroll
      for (int du = 0; du < 4; ++du) {
#pragma unroll
        for (int ks = 0; ks < 4; ++ks) {
          const int so = ((ks * 2 + hi) ^ vswz) << 3;
          bf16x8 vf = *(const bf16x8*)&Vs[cur][(du * 32 + l31) * 64 + so];
          bf16x8 pb = *(const bf16x8*)&paw[ks][0];
          accO[du] = __builtin_amdgcn_mfma_f32_32x32x16_bf16(vf, pb, accO[du], 0, 0, 0);
        }
      }
      __builtin_amdgcn_s_setprio(0);
    }
    __syncthreads();                     // drains staging; ends Vs[cur] reads
  }
#undef KSTAGE
#undef VSTAGE

  // ---- epilogue: finish denom across hi-pair, scale, pack b64 stores ----
  denom += __shfl_xor(denom, 32);
  const float inv = 1.0f / denom;
  ushort* op = AO + (bS + q0w + l31) * HIDDEN + h * HD + hi * 4;
#pragma unroll
  for (int du = 0; du < 4; ++du)
#pragma unroll
    for (int g = 0; g < 4; ++g) {
      uint2 u;
      u.x = cvtpk(accO[du][4 * g + 0] * inv, accO[du][4 * g + 1] * inv);
      u.y = cvtpk(accO[du][4 * g + 2] * inv, accO[du][4 * g + 3] * inv);
      *(uint2*)(op + du * 32 + g * 8) = u;
    }
}

// ---------------------------------------------------------------------------
extern "C" void kernel_launch(void* const* d_in, const int* in_sizes, int n_in,
                              void* d_out, int out_size, void* d_ws, size_t ws_size,
                              hipStream_t stream) {
  (void)in_sizes; (void)n_in; (void)out_size; (void)ws_size;
  const float* X   = (const float*)d_in[0];
  const int*   pos = (const int*)d_in[2];
  const float* Wq  = (const float*)d_in[3];
  const float* Wk  = (const float*)d_in[4];
  const float* Wv  = (const float*)d_in[5];
  const float* Wo  = (const float*)d_in[6];

  char* ws = (char*)d_ws;
  ushort* Xb    = (ushort*)(ws);                    // 33,554,432 B (aliased by AO)
  ushort* QKV   = (ushort*)(ws + 33554432);         // 50,331,648 B  [M][6144]
  ushort* BTqkv = (ushort*)(ws + 83886080);         // 50,331,648 B
  ushort* WoT   = (ushort*)(ws + 134217728);        // 33,554,432 B
  ushort* AO    = Xb;                               // X dead after QKV projection
  ushort* VtG   = BTqkv;                            // BTqkv dead after QKV GEMM

  const int M = BSZ * SEQ;  // 4096
  dim3 blk(256);

  hipFuncSetAttribute((const void*)gemm8p_kernel<1>,
                      hipFuncAttributeMaxDynamicSharedMemorySize, 131072);
  hipFuncSetAttribute((const void*)gemm8p_kernel<0>,
                      hipFuncAttributeMaxDynamicSharedMemorySize, 131072);

  // ---- pre-passes ----
  cvt_bf16_kernel<<<dim3((M * HIDDEN / 8 + 255) / 256), blk, 0, stream>>>(X, Xb, M * HIDDEN / 8);
  transpose_bf16_kernel<<<dim3(HIDDEN / 32, HIDDEN / 32), blk, 0, stream>>>(Wq, BTqkv, HIDDEN, HIDDEN);
  transpose_bf16_kernel<<<dim3((NKV * HD) / 32, HIDDEN / 32), blk, 0, stream>>>(
      Wk, BTqkv + (size_t)HIDDEN * HIDDEN, HIDDEN, NKV * HD);
  transpose_bf16_kernel<<<dim3((NKV * HD) / 32, HIDDEN / 32), blk, 0, stream>>>(
      Wv, BTqkv + (size_t)(HIDDEN + NKV * HD) * HIDDEN, HIDDEN, NKV * HD);
  transpose_bf16_kernel<<<dim3(HIDDEN / 32, HIDDEN / 32), blk, 0, stream>>>(Wo, WoT, HIDDEN, HIDDEN);

  // ---- fused QKV projection ----
  gemm8p_kernel<1><<<dim3((M / 256) * (QKVN / 256)), dim3(512), 131072, stream>>>(
      Xb, BTqkv, QKV, M, QKVN, HIDDEN);

  // ---- RoPE (Q scaled by 1/sqrt(128)*log2e; K unscaled) + V transpose ----
  rope_kernel<<<dim3((M * NH * 64) / 256), blk, 0, stream>>>(
      QKV, pos, NH, QKVLD, M * NH * 64, 0.12751731f);
  rope_kernel<<<dim3((M * NKV * 64) / 256), blk, 0, stream>>>(
      QKV + HIDDEN, pos, NKV, QKVLD, M * NKV * 64, 1.0f);
  transpose_v_kernel<<<dim3(SEQ / 32, HD / 32, BSZ * NKV), blk, 0, stream>>>(
      QKV + HIDDEN + NKV * HD, VtG);

  // ---- flash attention: 8 kh x 8 qtiles x 4 hq x 2 b = 512 blocks x 512 thr ----
  attn_kernel<<<dim3(512), dim3(512), 0, stream>>>(QKV, QKV + HIDDEN, VtG, AO);

  // ---- output projection -> fp32 d_out ----
  gemm8p_kernel<0><<<dim3((M / 256) * (HIDDEN / 256)), dim3(512), 131072, stream>>>(
      AO, WoT, d_out, M, HIDDEN, HIDDEN);
}